// Round 5
// baseline (415.583 us; speedup 1.0000x reference)
//
#include <hip/hip_runtime.h>
#include <math.h>

#define DIN 128
#define DOUT 64
#define GR 68               // 64x64 LDS row stride (floats), 16B-aligned rows

__device__ __forceinline__ float safe_pow(float d, float e) {
    float p = powf(d, e);
    return isinf(p) ? 0.0f : p;
}

__device__ __forceinline__ float dot4(float4 a, float4 b) {
    return a.x * b.x + a.y * b.y + a.z * b.z + a.w * b.w;
}

// C = A @ B for 64x64 LDS matrices, REQUIRES B symmetric (rows read as cols).
// k-rotated (k4 = (kk + t) & 15) so lanes hit different k-slices each step:
// spreads both operand reads across all 32 banks (row stride 4*GR = 16 mod 32
// would otherwise 8-way-conflict the B reads).
__device__ __forceinline__ void mm64(const float* A, const float* Bs, float* C, int t) {
    int ti = (t >> 4) * 4, tj = (t & 15) * 4;
    float acc[4][4] = {};
#pragma unroll
    for (int kk = 0; kk < 16; ++kk) {
        int k4 = (kk + t) & 15;
        float4 a[4], bb[4];
#pragma unroll
        for (int r = 0; r < 4; ++r) a[r] = *(const float4*)&A[(ti + r) * GR + k4 * 4];
#pragma unroll
        for (int c = 0; c < 4; ++c) bb[c] = *(const float4*)&Bs[(tj + c) * GR + k4 * 4];
#pragma unroll
        for (int r = 0; r < 4; ++r)
#pragma unroll
            for (int c = 0; c < 4; ++c) acc[r][c] += dot4(a[r], bb[c]);
    }
#pragma unroll
    for (int r = 0; r < 4; ++r)
#pragma unroll
        for (int c = 0; c < 4; ++c) C[(ti + r) * GR + tj + c] = acc[r][c];
}

// ---------------------------------------------------------------------------
// Bjorck via Gram-domain iteration (single workgroup):
//   G = W W^T; sigma = sqrt(lambda_max(G)) via squared-operator power method:
//     H = G@G; H2 = H@H (trace-scaled); 7 raw iters + Rayleigh quotient
//     -> lambda_H2 = sigma^8, convergence ~ ratio^112, no sqrt/div in chain.
//   A0 = G/(1.21*lam); iterate: B=1.5I-0.5A; P=P@B; A=A@B@B; Wo = sc * P @ W
// ---------------------------------------------------------------------------
__global__ __launch_bounds__(256) void bjorck_kernel(const float* __restrict__ W,
                                                     float* __restrict__ Wo) {
    __shared__ __align__(16) float A0[DOUT * GR];
    __shared__ __align__(16) float A1[DOUT * GR];
    __shared__ __align__(16) float P0[DOUT * GR];
    __shared__ __align__(16) float P1[DOUT * GR];
    __shared__ __align__(16) float Bm[DOUT * GR];
    __shared__ float sc_sh, rs_sh;
    int t = threadIdx.x;

    // G = W W^T  (W straight from global; 32KB, cache-resident)
    {
        int ti = (t >> 4) * 4, tj = (t & 15) * 4;
        float acc[4][4] = {};
        for (int k4 = 0; k4 < DIN / 4; ++k4) {
            float4 a[4], bb[4];
#pragma unroll
            for (int r = 0; r < 4; ++r) a[r] = *(const float4*)&W[(ti + r) * DIN + k4 * 4];
#pragma unroll
            for (int c = 0; c < 4; ++c) bb[c] = *(const float4*)&W[(tj + c) * DIN + k4 * 4];
#pragma unroll
            for (int r = 0; r < 4; ++r)
#pragma unroll
                for (int c = 0; c < 4; ++c) acc[r][c] += dot4(a[r], bb[c]);
        }
#pragma unroll
        for (int r = 0; r < 4; ++r)
#pragma unroll
            for (int c = 0; c < 4; ++c) A0[(ti + r) * GR + tj + c] = acc[r][c];
    }
    __syncthreads();

    mm64(A0, A0, A1, t);          // H = G^2
    __syncthreads();
    mm64(A1, A1, P0, t);          // H2 = G^4
    __syncthreads();

    // squared-operator power iteration on H2 within wave 0
    if (t < 64) {
        // trace of H2 for overflow-safe scaling (lambda_scaled in (1/64, 1])
        float tr = P0[t * GR + t];
#pragma unroll
        for (int d = 1; d < 64; d <<= 1) tr += __shfl_xor(tr, d);
        float inv_tr = 1.0f / tr;
        float4 g4[16];
#pragma unroll
        for (int j4 = 0; j4 < 16; ++j4) {
            float4 v = *(const float4*)&P0[t * GR + j4 * 4];
            v.x *= inv_tr; v.y *= inv_tr; v.z *= inv_tr; v.w *= inv_tr;
            g4[j4] = v;
        }
        unsigned h = (unsigned)t * 2654435761u;
        float xv = 0.5f + (float)((h >> 17) & 0x7fff) * (1.0f / 32768.0f);
        float yv = 0.f;
        for (int it = 0; it < 8; ++it) {
            float p0 = 0.f, p1 = 0.f, p2 = 0.f, p3 = 0.f;
#pragma unroll
            for (int j4 = 0; j4 < 16; ++j4) {
                float4 xx;
                xx.x = __shfl(xv, j4 * 4 + 0);
                xx.y = __shfl(xv, j4 * 4 + 1);
                xx.z = __shfl(xv, j4 * 4 + 2);
                xx.w = __shfl(xv, j4 * 4 + 3);
                float dd = dot4(g4[j4], xx);
                if (j4 < 4) p0 += dd; else if (j4 < 8) p1 += dd;
                else if (j4 < 12) p2 += dd; else p3 += dd;
            }
            yv = (p0 + p1) + (p2 + p3);
            if (it < 7) xv = yv;      // raw iteration, no normalization
        }
        // Rayleigh: lambda_scaled = (x.y)/(x.x); x = y7, y = H2s y7
        float num = xv * yv, den = xv * xv;
#pragma unroll
        for (int d = 1; d < 64; d <<= 1) {
            num += __shfl_xor(num, d);
            den += __shfl_xor(den, d);
        }
        if (t == 0) {
            float lam_h2 = tr * num / den;        // = sigma^8
            float sig = powf(lam_h2, 0.125f);     // sigma_max(W)
            sc_sh = 1.0f / (1.1f * sig);
            rs_sh = 1.0f / (1.21f * sig * sig);
        }
    }
    __syncthreads();
    float rs = rs_sh;
    for (int q = t; q < DOUT * 64; q += 256) {
        int i = q >> 6, j = q & 63;
        A0[i * GR + j] *= rs;
    }
    __syncthreads();

    float *Acur = A0, *Aalt = A1, *Pcur = P0, *Palt = P1;
    for (int it = 0; it < 5; ++it) {
        for (int q = t; q < DOUT * 64; q += 256) {
            int i = q >> 6, j = q & 63;
            Bm[i * GR + j] = (i == j ? 1.5f : 0.0f) - 0.5f * Acur[i * GR + j];
        }
        __syncthreads();
        if (it == 0) {
            for (int q = t; q < DOUT * 64; q += 256) {
                int i = q >> 6, j = q & 63;
                Pcur[i * GR + j] = Bm[i * GR + j];
            }
        } else {
            mm64(Pcur, Bm, Palt, t);
        }
        __syncthreads();
        if (it != 0) { float* tmp = Pcur; Pcur = Palt; Palt = tmp; }
        mm64(Bm, Bm, Palt, t);        // B^2 into dead buffer
        __syncthreads();
        mm64(Acur, Palt, Aalt, t);    // A = A @ B^2
        __syncthreads();
        float* tmp = Acur; Acur = Aalt; Aalt = tmp;
    }

    // Wo = sc * P @ W
    float sc = sc_sh;
    {
        int i0 = (t >> 4) * 4;
        int k0 = (t & 15) * 8;
        float4 acc0[4] = {}, acc1[4] = {};
        for (int j = 0; j < 64; ++j) {
            float4 w0 = *(const float4*)&W[j * DIN + k0];
            float4 w1 = *(const float4*)&W[j * DIN + k0 + 4];
#pragma unroll
            for (int r = 0; r < 4; ++r) {
                float pv = Pcur[(i0 + r) * GR + j];
                acc0[r].x += pv * w0.x; acc0[r].y += pv * w0.y;
                acc0[r].z += pv * w0.z; acc0[r].w += pv * w0.w;
                acc1[r].x += pv * w1.x; acc1[r].y += pv * w1.y;
                acc1[r].z += pv * w1.z; acc1[r].w += pv * w1.w;
            }
        }
#pragma unroll
        for (int r = 0; r < 4; ++r) {
            float4 o0 = make_float4(sc * acc0[r].x, sc * acc0[r].y, sc * acc0[r].z, sc * acc0[r].w);
            float4 o1 = make_float4(sc * acc1[r].x, sc * acc1[r].y, sc * acc1[r].z, sc * acc1[r].w);
            *(float4*)&Wo[(i0 + r) * DIN + k0] = o0;
            *(float4*)&Wo[(i0 + r) * DIN + k0 + 4] = o1;
        }
    }
}

// ---------------------------------------------------------------------------
// per-node prep
// ---------------------------------------------------------------------------
__global__ void node_prep(const float* __restrict__ diags,
                          const float* m1, const float* m2, const float* m3,
                          const float* e1, const float* e2, const float* e3,
                          float* __restrict__ d_e2m, float* __restrict__ d_e3p,
                          float* __restrict__ gso2, int n) {
    int i = blockIdx.x * blockDim.x + threadIdx.x;
    if (i >= n) return;
    float d = diags[i];
    float p1 = safe_pow(d, e1[0]);
    float p2 = safe_pow(d, e2[0]);
    float p3 = safe_pow(d, e3[0]);
    float vm2 = m2[0];
    d_e2m[i] = vm2 * p2;
    d_e3p[i] = p3;
    gso2[i] = m1[0] * p1 + vm2 * p2 * p3 + m3[0];
}

// ---------------------------------------------------------------------------
// xw = x @ Wo^T — register-tiled GEMM (64-node tile, 4x4 per thread)
// ---------------------------------------------------------------------------
#define XN 64
#define XS 132
__global__ __launch_bounds__(256) void xw_kernel(const float* __restrict__ x,
                                                 const float* __restrict__ Wo,
                                                 float* __restrict__ xw, int n) {
    __shared__ __align__(16) float xs[XN * XS];
    __shared__ __align__(16) float ws[DOUT * XS];
    int t = threadIdx.x;
    int base = blockIdx.x * XN;
    for (int f = t; f < DOUT * (DIN / 4); f += 256) {
        int r = f >> 5, c = f & 31;
        *(float4*)&ws[r * XS + c * 4] = *(const float4*)&Wo[r * DIN + c * 4];
    }
    for (int f = t; f < XN * (DIN / 4); f += 256) {
        int r = f >> 5, c = f & 31;
        int node = base + r;
        float4 v = make_float4(0.f, 0.f, 0.f, 0.f);
        if (node < n) v = *(const float4*)&x[(size_t)node * DIN + c * 4];
        *(float4*)&xs[r * XS + c * 4] = v;
    }
    __syncthreads();
    int tn = t >> 4;
    int td = t & 15;
    float acc[4][4] = {};
#pragma unroll 2
    for (int k4 = 0; k4 < DIN / 4; ++k4) {
        float4 a[4], w[4];
#pragma unroll
        for (int r = 0; r < 4; ++r) a[r] = *(const float4*)&xs[(tn * 4 + r) * XS + k4 * 4];
#pragma unroll
        for (int c = 0; c < 4; ++c) w[c] = *(const float4*)&ws[(td + c * 16) * XS + k4 * 4];
#pragma unroll
        for (int r = 0; r < 4; ++r)
#pragma unroll
            for (int c = 0; c < 4; ++c) acc[r][c] += dot4(a[r], w[c]);
    }
#pragma unroll
    for (int r = 0; r < 4; ++r) {
        int node = base + tn * 4 + r;
        if (node >= n) break;
#pragma unroll
        for (int c = 0; c < 4; ++c)
            xw[(size_t)node * DOUT + td + c * 16] = acc[r][c];
    }
}

// ---------------------------------------------------------------------------
// histogram of destination column
// ---------------------------------------------------------------------------
__global__ __launch_bounds__(256) void hist_kernel(const int* __restrict__ ei,
                                                   int* __restrict__ counts, int e_cnt) {
    int e = blockIdx.x * blockDim.x + threadIdx.x;
    if (e >= e_cnt) return;
    atomicAdd(&counts[ei[e_cnt + e]], 1);
}

// ---------------------------------------------------------------------------
// 3-phase scan
// ---------------------------------------------------------------------------
__global__ __launch_bounds__(256) void scan_partial(const int* __restrict__ counts,
                                                    int* __restrict__ partials, int n) {
    __shared__ int wsum[4];
    int b = blockIdx.x, t = threadIdx.x;
    int base = b * 1024 + t * 4;
    int s = 0;
    if (base + 4 <= n) {
        int4 v = *(const int4*)&counts[base];
        s = v.x + v.y + v.z + v.w;
    } else {
        for (int i = base; i < n; ++i) s += counts[i];
    }
#pragma unroll
    for (int d = 1; d < 64; d <<= 1) s += __shfl_xor(s, d);
    if ((t & 63) == 0) wsum[t >> 6] = s;
    __syncthreads();
    if (t == 0) partials[b] = wsum[0] + wsum[1] + wsum[2] + wsum[3];
}

__global__ __launch_bounds__(128) void scan_mid(const int* __restrict__ partials,
                                                int* __restrict__ blk_off, int nb) {
    __shared__ int sh[128];
    int t = threadIdx.x;
    int v = (t < nb) ? partials[t] : 0;
    sh[t] = v;
    __syncthreads();
    for (int d = 1; d < 128; d <<= 1) {
        int u = (t >= d) ? sh[t - d] : 0;
        __syncthreads();
        sh[t] += u;
        __syncthreads();
    }
    if (t < nb) blk_off[t] = sh[t] - v;
}

__global__ __launch_bounds__(256) void scan_write(const int* __restrict__ counts,
                                                  const int* __restrict__ blk_off,
                                                  int* __restrict__ offsets,
                                                  int* __restrict__ cursors,
                                                  int n, int e_cnt) {
    __shared__ int sh[256];
    int b = blockIdx.x, t = threadIdx.x;
    int base = b * 1024 + t * 4;
    int4 v = make_int4(0, 0, 0, 0);
    bool full = (base + 4 <= n);
    if (full) {
        v = *(const int4*)&counts[base];
    } else {
        int* vv = &v.x;
        for (int i = 0; i < 4; ++i) vv[i] = (base + i < n) ? counts[base + i] : 0;
    }
    int s = v.x + v.y + v.z + v.w;
    sh[t] = s;
    __syncthreads();
    for (int d = 1; d < 256; d <<= 1) {
        int u = (t >= d) ? sh[t - d] : 0;
        __syncthreads();
        sh[t] += u;
        __syncthreads();
    }
    int run = blk_off[b] + sh[t] - s;
    int4 o;
    o.x = run;
    o.y = run + v.x;
    o.z = o.y + v.y;
    o.w = o.z + v.z;
    if (full) {
        *(int4*)&offsets[base] = o;
        *(int4*)&cursors[base] = o;
    } else {
        int* oo = &o.x;
        for (int i = 0; i < 4; ++i)
            if (base + i < n) { offsets[base + i] = oo[i]; cursors[base + i] = oo[i]; }
    }
    if (b == 0 && t == 0) offsets[n] = e_cnt;
}

// ---------------------------------------------------------------------------
// reorder edges into CSR-by-col as interleaved (src, weight) int2 pairs
// ---------------------------------------------------------------------------
__global__ __launch_bounds__(256) void reorder_kernel(const int* __restrict__ ei,
                                                      const float* __restrict__ d_e2m,
                                                      const float* __restrict__ d_e3p,
                                                      int* __restrict__ cursors,
                                                      int2* __restrict__ pairs, int e_cnt) {
    int e = blockIdx.x * blockDim.x + threadIdx.x;
    if (e >= e_cnt) return;
    int row = ei[e];
    int col = ei[e_cnt + e];
    int pos = atomicAdd(&cursors[col], 1);
    int2 p;
    p.x = row;
    p.y = __float_as_int(d_e2m[row] * d_e3p[col]);
    pairs[pos] = p;
}

// ---------------------------------------------------------------------------
// fused gather + self-loop + bias + log-softmax; one wave per node
// ---------------------------------------------------------------------------
__global__ __launch_bounds__(256) void gather_kernel(const int* __restrict__ offsets,
                                                     const int2* __restrict__ pairs,
                                                     const float* __restrict__ xw,
                                                     const float* __restrict__ gso2,
                                                     const float* __restrict__ b,
                                                     float* __restrict__ out, int n) {
    int lane = threadIdx.x & 63;
    int node = blockIdx.x * 4 + (threadIdx.x >> 6);
    if (node >= n) return;
    int lo = offsets[node], hi = offsets[node + 1];
    float v = gso2[node] * xw[(size_t)node * DOUT + lane] + 2.0f * b[lane];
    int i = lo;
    for (; i + 4 <= hi; i += 4) {
        int2 p0 = pairs[i], p1 = pairs[i + 1], p2 = pairs[i + 2], p3 = pairs[i + 3];
        float a0 = xw[(size_t)p0.x * DOUT + lane];
        float a1 = xw[(size_t)p1.x * DOUT + lane];
        float a2 = xw[(size_t)p2.x * DOUT + lane];
        float a3 = xw[(size_t)p3.x * DOUT + lane];
        v += __int_as_float(p0.y) * a0 + __int_as_float(p1.y) * a1
           + __int_as_float(p2.y) * a2 + __int_as_float(p3.y) * a3;
    }
    for (; i < hi; ++i) {
        int2 p = pairs[i];
        v += __int_as_float(p.y) * xw[(size_t)p.x * DOUT + lane];
    }
    float m = v;
#pragma unroll
    for (int d = 1; d < 64; d <<= 1) m = fmaxf(m, __shfl_xor(m, d));
    float s = expf(v - m);
#pragma unroll
    for (int d = 1; d < 64; d <<= 1) s += __shfl_xor(s, d);
    out[(size_t)node * DOUT + lane] = v - m - logf(s);
}

// ---------------------------------------------------------------------------
extern "C" void kernel_launch(void* const* d_in, const int* in_sizes, int n_in,
                              void* d_out, int out_size, void* d_ws, size_t ws_size,
                              hipStream_t stream) {
    const float* x     = (const float*)d_in[0];
    const int*   ei    = (const int*)d_in[1];
    const float* diags = (const float*)d_in[3];
    const float* W     = (const float*)d_in[4];
    const float* b     = (const float*)d_in[5];
    const float* m1    = (const float*)d_in[6];
    const float* m2    = (const float*)d_in[7];
    const float* m3    = (const float*)d_in[8];
    const float* e1    = (const float*)d_in[9];
    const float* e2    = (const float*)d_in[10];
    const float* e3    = (const float*)d_in[11];
    float* out = (float*)d_out;

    const int n = in_sizes[3];          // 100000
    const int e_cnt = in_sizes[1] / 2;  // 1600000
    const int nb = (n + 1023) / 1024;   // scan blocks

    char* ws = (char*)d_ws;
    float* Wo       = (float*)ws;                       // 8K floats
    float* d_e2m    = (float*)(ws + 32768);             // n
    float* d_e3p    = d_e2m + n;                        // n
    float* gso2     = d_e3p + n;                        // n
    float* xw       = gso2 + n;                         // n*64
    int*   counts   = (int*)(xw + (size_t)n * DOUT);    // n
    int*   offsets  = counts + n;                       // n+4
    int*   cursors  = offsets + n + 4;                  // n
    int*   partials = cursors + n;                      // 128
    int*   blk_off  = partials + 128;                   // 128
    uintptr_t pp = ((uintptr_t)(blk_off + 128) + 15) & ~(uintptr_t)15;
    int2*  pairs    = (int2*)pp;                        // e_cnt

    hipMemsetAsync(counts, 0, (size_t)n * sizeof(int), stream);

    bjorck_kernel<<<1, 256, 0, stream>>>(W, Wo);
    node_prep<<<(n + 255) / 256, 256, 0, stream>>>(diags, m1, m2, m3, e1, e2, e3,
                                                   d_e2m, d_e3p, gso2, n);
    xw_kernel<<<(n + XN - 1) / XN, 256, 0, stream>>>(x, Wo, xw, n);
    hist_kernel<<<(e_cnt + 255) / 256, 256, 0, stream>>>(ei, counts, e_cnt);
    scan_partial<<<nb, 256, 0, stream>>>(counts, partials, n);
    scan_mid<<<1, 128, 0, stream>>>(partials, blk_off, nb);
    scan_write<<<nb, 256, 0, stream>>>(counts, blk_off, offsets, cursors, n, e_cnt);
    reorder_kernel<<<(e_cnt + 255) / 256, 256, 0, stream>>>(ei, d_e2m, d_e3p,
                                                            cursors, pairs, e_cnt);
    gather_kernel<<<(n + 3) / 4, 256, 0, stream>>>(offsets, pairs, xw, gso2, b,
                                                   out, n);
}

// Round 6
// 412.889 us; speedup vs baseline: 1.0065x; 1.0065x over previous
//
#include <hip/hip_runtime.h>
#include <math.h>

#define DIN 128
#define DOUT 64
#define GR 68               // 64x64 LDS row stride (floats), 16B-aligned rows

__device__ __forceinline__ float safe_pow(float d, float e) {
    float p = powf(d, e);
    return isinf(p) ? 0.0f : p;
}

__device__ __forceinline__ float dot4(float4 a, float4 b) {
    return a.x * b.x + a.y * b.y + a.z * b.z + a.w * b.w;
}

// C = A @ B for 64x64 LDS matrices; REQUIRES B symmetric (rows read as cols).
// Thread t -> C rows ti..ti+3 (ti=(t>>4)*4), cols {m,m+16,m+32,m+48} (m=t&15).
// B-row reads at 16-strided rows hit banks 4m mod 32 -> 2-way max (free);
// k4 stays a compile-time constant (full unroll) so ds_read_b128 gets
// immediate offsets (round-5 lesson: runtime-rotated addresses cost 2x).
__device__ __forceinline__ void mm64(const float* __restrict__ A,
                                     const float* __restrict__ Bs,
                                     float* __restrict__ C, int t) {
    int ti = (t >> 4) * 4, m = t & 15;
    float acc[4][4] = {};
#pragma unroll
    for (int k4 = 0; k4 < 16; ++k4) {
        float4 a[4], bb[4];
#pragma unroll
        for (int r = 0; r < 4; ++r) a[r] = *(const float4*)&A[(ti + r) * GR + k4 * 4];
#pragma unroll
        for (int c = 0; c < 4; ++c) bb[c] = *(const float4*)&Bs[(m + c * 16) * GR + k4 * 4];
#pragma unroll
        for (int r = 0; r < 4; ++r)
#pragma unroll
            for (int c = 0; c < 4; ++c) acc[r][c] += dot4(a[r], bb[c]);
    }
#pragma unroll
    for (int r = 0; r < 4; ++r)
#pragma unroll
        for (int c = 0; c < 4; ++c) C[(ti + r) * GR + m + c * 16] = acc[r][c];
}

// C1 = A1 @ Bs and C2 = A2 @ Bs in ONE pass (shared Bs reads).
__device__ __forceinline__ void mm64_dual(const float* __restrict__ A1,
                                          const float* __restrict__ A2,
                                          const float* __restrict__ Bs,
                                          float* __restrict__ C1,
                                          float* __restrict__ C2, int t) {
    int ti = (t >> 4) * 4, m = t & 15;
    float acc1[4][4] = {}, acc2[4][4] = {};
#pragma unroll
    for (int k4 = 0; k4 < 16; ++k4) {
        float4 bb[4];
#pragma unroll
        for (int c = 0; c < 4; ++c) bb[c] = *(const float4*)&Bs[(m + c * 16) * GR + k4 * 4];
#pragma unroll
        for (int r = 0; r < 4; ++r) {
            float4 a = *(const float4*)&A1[(ti + r) * GR + k4 * 4];
#pragma unroll
            for (int c = 0; c < 4; ++c) acc1[r][c] += dot4(a, bb[c]);
        }
#pragma unroll
        for (int r = 0; r < 4; ++r) {
            float4 a = *(const float4*)&A2[(ti + r) * GR + k4 * 4];
#pragma unroll
            for (int c = 0; c < 4; ++c) acc2[r][c] += dot4(a, bb[c]);
        }
    }
#pragma unroll
    for (int r = 0; r < 4; ++r)
#pragma unroll
        for (int c = 0; c < 4; ++c) {
            C1[(ti + r) * GR + m + c * 16] = acc1[r][c];
            C2[(ti + r) * GR + m + c * 16] = acc2[r][c];
        }
}

// ---------------------------------------------------------------------------
// Bjorck via Gram-domain iteration (single workgroup):
//   G = W W^T; sigma via squared-operator power method on H2=G^4 (trace-scaled,
//   8 raw iters + Rayleigh). A0 = G/(1.21 sigma^2).
//   per iter: B = 1.5I - 0.5A; P <- P@B; A <- (A@B)@B  (all share B-operand;
//   P@B and A@B fused in one dual-pass). it0: P=B (copy); it4: P-update only.
//   Wo = sc * P @ W.
// ---------------------------------------------------------------------------
__global__ __launch_bounds__(256) void bjorck_kernel(const float* __restrict__ W,
                                                     float* __restrict__ Wo) {
    __shared__ __align__(16) float A0s[DOUT * GR];
    __shared__ __align__(16) float A1s[DOUT * GR];
    __shared__ __align__(16) float P0s[DOUT * GR];
    __shared__ __align__(16) float P1s[DOUT * GR];
    __shared__ __align__(16) float Bm[DOUT * GR];
    __shared__ float sc_sh, rs_sh;
    int t = threadIdx.x;

    // G = W W^T  (W straight from global; 32KB, cache-resident)
    {
        int ti = (t >> 4) * 4, m = t & 15;
        float acc[4][4] = {};
        for (int k4 = 0; k4 < DIN / 4; ++k4) {
            float4 a[4], bb[4];
#pragma unroll
            for (int r = 0; r < 4; ++r) a[r] = *(const float4*)&W[(ti + r) * DIN + k4 * 4];
#pragma unroll
            for (int c = 0; c < 4; ++c) bb[c] = *(const float4*)&W[(m + c * 16) * DIN + k4 * 4];
#pragma unroll
            for (int r = 0; r < 4; ++r)
#pragma unroll
                for (int c = 0; c < 4; ++c) acc[r][c] += dot4(a[r], bb[c]);
        }
#pragma unroll
        for (int r = 0; r < 4; ++r)
#pragma unroll
            for (int c = 0; c < 4; ++c) A0s[(ti + r) * GR + m + c * 16] = acc[r][c];
    }
    __syncthreads();

    mm64(A0s, A0s, A1s, t);          // H = G^2
    __syncthreads();
    mm64(A1s, A1s, P0s, t);          // H2 = G^4
    __syncthreads();

    // squared-operator power iteration on H2 within wave 0
    if (t < 64) {
        float tr = P0s[t * GR + t];
#pragma unroll
        for (int d = 1; d < 64; d <<= 1) tr += __shfl_xor(tr, d);
        float inv_tr = 1.0f / tr;
        float4 g4[16];
#pragma unroll
        for (int j4 = 0; j4 < 16; ++j4) {
            float4 v = *(const float4*)&P0s[t * GR + j4 * 4];
            v.x *= inv_tr; v.y *= inv_tr; v.z *= inv_tr; v.w *= inv_tr;
            g4[j4] = v;
        }
        unsigned h = (unsigned)t * 2654435761u;
        float xv = 0.5f + (float)((h >> 17) & 0x7fff) * (1.0f / 32768.0f);
        float yv = 0.f;
        for (int it = 0; it < 8; ++it) {
            float p0 = 0.f, p1 = 0.f, p2 = 0.f, p3 = 0.f;
#pragma unroll
            for (int j4 = 0; j4 < 16; ++j4) {
                float4 xx;
                xx.x = __shfl(xv, j4 * 4 + 0);
                xx.y = __shfl(xv, j4 * 4 + 1);
                xx.z = __shfl(xv, j4 * 4 + 2);
                xx.w = __shfl(xv, j4 * 4 + 3);
                float dd = dot4(g4[j4], xx);
                if (j4 < 4) p0 += dd; else if (j4 < 8) p1 += dd;
                else if (j4 < 12) p2 += dd; else p3 += dd;
            }
            yv = (p0 + p1) + (p2 + p3);
            if (it < 7) xv = yv;      // raw iteration, no normalization
        }
        float num = xv * yv, den = xv * xv;
#pragma unroll
        for (int d = 1; d < 64; d <<= 1) {
            num += __shfl_xor(num, d);
            den += __shfl_xor(den, d);
        }
        if (t == 0) {
            float lam_h2 = tr * num / den;        // = sigma^8
            float sig = powf(lam_h2, 0.125f);     // sigma_max(W)
            sc_sh = 1.0f / (1.1f * sig);
            rs_sh = 1.0f / (1.21f * sig * sig);
        }
    }
    __syncthreads();
    float rs = rs_sh;
    for (int q = t; q < DOUT * 64; q += 256) {
        int i = q >> 6, j = q & 63;
        A0s[i * GR + j] *= rs;
    }
    __syncthreads();

    float *Ac = A0s, *Pc = P0s, *s1 = A1s, *s2 = P1s;
    for (int it = 0; it < 5; ++it) {
        // Bm = 1.5I - 0.5*Ac ; it0 also initializes P := Bm
        for (int q = t; q < DOUT * 64; q += 256) {
            int i = q >> 6, j = q & 63;
            float v = (i == j ? 1.5f : 0.0f) - 0.5f * Ac[i * GR + j];
            Bm[i * GR + j] = v;
            if (it == 0) Pc[i * GR + j] = v;
        }
        __syncthreads();
        if (it == 0) {
            mm64(Ac, Bm, s1, t);                 // T = A@B
            __syncthreads();
            mm64(s1, Bm, s2, t);                 // Anew = T@B
            __syncthreads();
            float* na = s2; s2 = s1; s1 = Ac; Ac = na;
        } else if (it < 4) {
            mm64_dual(Pc, Ac, Bm, s1, s2, t);    // Pnew = s1, T = s2
            __syncthreads();
            mm64(s2, Bm, Pc, t);                 // Anew into dead old-P
            __syncthreads();
            float* na = Pc; float* np = s1; s1 = Ac; Ac = na; Pc = np;
        } else {
            mm64(Pc, Bm, s1, t);                 // Pfinal
            __syncthreads();
        }
    }
    const float* Pf = s1;

    // Wo = sc * Pf @ W
    float sc = sc_sh;
    {
        int i0 = (t >> 4) * 4;
        int k0 = (t & 15) * 8;
        float4 acc0[4] = {}, acc1[4] = {};
        for (int j = 0; j < 64; ++j) {
            float4 w0 = *(const float4*)&W[j * DIN + k0];
            float4 w1 = *(const float4*)&W[j * DIN + k0 + 4];
#pragma unroll
            for (int r = 0; r < 4; ++r) {
                float pv = Pf[(i0 + r) * GR + j];
                acc0[r].x += pv * w0.x; acc0[r].y += pv * w0.y;
                acc0[r].z += pv * w0.z; acc0[r].w += pv * w0.w;
                acc1[r].x += pv * w1.x; acc1[r].y += pv * w1.y;
                acc1[r].z += pv * w1.z; acc1[r].w += pv * w1.w;
            }
        }
#pragma unroll
        for (int r = 0; r < 4; ++r) {
            float4 o0 = make_float4(sc * acc0[r].x, sc * acc0[r].y, sc * acc0[r].z, sc * acc0[r].w);
            float4 o1 = make_float4(sc * acc1[r].x, sc * acc1[r].y, sc * acc1[r].z, sc * acc1[r].w);
            *(float4*)&Wo[(i0 + r) * DIN + k0] = o0;
            *(float4*)&Wo[(i0 + r) * DIN + k0 + 4] = o1;
        }
    }
}

// ---------------------------------------------------------------------------
// per-node prep
// ---------------------------------------------------------------------------
__global__ void node_prep(const float* __restrict__ diags,
                          const float* m1, const float* m2, const float* m3,
                          const float* e1, const float* e2, const float* e3,
                          float* __restrict__ d_e2m, float* __restrict__ d_e3p,
                          float* __restrict__ gso2, int n) {
    int i = blockIdx.x * blockDim.x + threadIdx.x;
    if (i >= n) return;
    float d = diags[i];
    float p1 = safe_pow(d, e1[0]);
    float p2 = safe_pow(d, e2[0]);
    float p3 = safe_pow(d, e3[0]);
    float vm2 = m2[0];
    d_e2m[i] = vm2 * p2;
    d_e3p[i] = p3;
    gso2[i] = m1[0] * p1 + vm2 * p2 * p3 + m3[0];
}

// ---------------------------------------------------------------------------
// xw = x @ Wo^T — register-tiled GEMM (64-node tile, 4x4 per thread)
// ---------------------------------------------------------------------------
#define XN 64
#define XS 132
__global__ __launch_bounds__(256) void xw_kernel(const float* __restrict__ x,
                                                 const float* __restrict__ Wo,
                                                 float* __restrict__ xw, int n) {
    __shared__ __align__(16) float xs[XN * XS];
    __shared__ __align__(16) float ws[DOUT * XS];
    int t = threadIdx.x;
    int base = blockIdx.x * XN;
    for (int f = t; f < DOUT * (DIN / 4); f += 256) {
        int r = f >> 5, c = f & 31;
        *(float4*)&ws[r * XS + c * 4] = *(const float4*)&Wo[r * DIN + c * 4];
    }
    for (int f = t; f < XN * (DIN / 4); f += 256) {
        int r = f >> 5, c = f & 31;
        int node = base + r;
        float4 v = make_float4(0.f, 0.f, 0.f, 0.f);
        if (node < n) v = *(const float4*)&x[(size_t)node * DIN + c * 4];
        *(float4*)&xs[r * XS + c * 4] = v;
    }
    __syncthreads();
    int tn = t >> 4;
    int td = t & 15;
    float acc[4][4] = {};
#pragma unroll 2
    for (int k4 = 0; k4 < DIN / 4; ++k4) {
        float4 a[4], w[4];
#pragma unroll
        for (int r = 0; r < 4; ++r) a[r] = *(const float4*)&xs[(tn * 4 + r) * XS + k4 * 4];
#pragma unroll
        for (int c = 0; c < 4; ++c) w[c] = *(const float4*)&ws[(td + c * 16) * XS + k4 * 4];
#pragma unroll
        for (int r = 0; r < 4; ++r)
#pragma unroll
            for (int c = 0; c < 4; ++c) acc[r][c] += dot4(a[r], w[c]);
    }
#pragma unroll
    for (int r = 0; r < 4; ++r) {
        int node = base + tn * 4 + r;
        if (node >= n) break;
#pragma unroll
        for (int c = 0; c < 4; ++c)
            xw[(size_t)node * DOUT + td + c * 16] = acc[r][c];
    }
}

// ---------------------------------------------------------------------------
// histogram of destination column
// ---------------------------------------------------------------------------
__global__ __launch_bounds__(256) void hist_kernel(const int* __restrict__ ei,
                                                   int* __restrict__ counts, int e_cnt) {
    int e = blockIdx.x * blockDim.x + threadIdx.x;
    if (e >= e_cnt) return;
    atomicAdd(&counts[ei[e_cnt + e]], 1);
}

// ---------------------------------------------------------------------------
// 3-phase scan
// ---------------------------------------------------------------------------
__global__ __launch_bounds__(256) void scan_partial(const int* __restrict__ counts,
                                                    int* __restrict__ partials, int n) {
    __shared__ int wsum[4];
    int b = blockIdx.x, t = threadIdx.x;
    int base = b * 1024 + t * 4;
    int s = 0;
    if (base + 4 <= n) {
        int4 v = *(const int4*)&counts[base];
        s = v.x + v.y + v.z + v.w;
    } else {
        for (int i = base; i < n; ++i) s += counts[i];
    }
#pragma unroll
    for (int d = 1; d < 64; d <<= 1) s += __shfl_xor(s, d);
    if ((t & 63) == 0) wsum[t >> 6] = s;
    __syncthreads();
    if (t == 0) partials[b] = wsum[0] + wsum[1] + wsum[2] + wsum[3];
}

__global__ __launch_bounds__(128) void scan_mid(const int* __restrict__ partials,
                                                int* __restrict__ blk_off, int nb) {
    __shared__ int sh[128];
    int t = threadIdx.x;
    int v = (t < nb) ? partials[t] : 0;
    sh[t] = v;
    __syncthreads();
    for (int d = 1; d < 128; d <<= 1) {
        int u = (t >= d) ? sh[t - d] : 0;
        __syncthreads();
        sh[t] += u;
        __syncthreads();
    }
    if (t < nb) blk_off[t] = sh[t] - v;
}

__global__ __launch_bounds__(256) void scan_write(const int* __restrict__ counts,
                                                  const int* __restrict__ blk_off,
                                                  int* __restrict__ offsets,
                                                  int* __restrict__ cursors,
                                                  int n, int e_cnt) {
    __shared__ int sh[256];
    int b = blockIdx.x, t = threadIdx.x;
    int base = b * 1024 + t * 4;
    int4 v = make_int4(0, 0, 0, 0);
    bool full = (base + 4 <= n);
    if (full) {
        v = *(const int4*)&counts[base];
    } else {
        int* vv = &v.x;
        for (int i = 0; i < 4; ++i) vv[i] = (base + i < n) ? counts[base + i] : 0;
    }
    int s = v.x + v.y + v.z + v.w;
    sh[t] = s;
    __syncthreads();
    for (int d = 1; d < 256; d <<= 1) {
        int u = (t >= d) ? sh[t - d] : 0;
        __syncthreads();
        sh[t] += u;
        __syncthreads();
    }
    int run = blk_off[b] + sh[t] - s;
    int4 o;
    o.x = run;
    o.y = run + v.x;
    o.z = o.y + v.y;
    o.w = o.z + v.z;
    if (full) {
        *(int4*)&offsets[base] = o;
        *(int4*)&cursors[base] = o;
    } else {
        int* oo = &o.x;
        for (int i = 0; i < 4; ++i)
            if (base + i < n) { offsets[base + i] = oo[i]; cursors[base + i] = oo[i]; }
    }
    if (b == 0 && t == 0) offsets[n] = e_cnt;
}

// ---------------------------------------------------------------------------
// reorder edges into CSR-by-col as interleaved (src, weight) int2 pairs
// ---------------------------------------------------------------------------
__global__ __launch_bounds__(256) void reorder_kernel(const int* __restrict__ ei,
                                                      const float* __restrict__ d_e2m,
                                                      const float* __restrict__ d_e3p,
                                                      int* __restrict__ cursors,
                                                      int2* __restrict__ pairs, int e_cnt) {
    int e = blockIdx.x * blockDim.x + threadIdx.x;
    if (e >= e_cnt) return;
    int row = ei[e];
    int col = ei[e_cnt + e];
    int pos = atomicAdd(&cursors[col], 1);
    int2 p;
    p.x = row;
    p.y = __float_as_int(d_e2m[row] * d_e3p[col]);
    pairs[pos] = p;
}

// ---------------------------------------------------------------------------
// fused gather + self-loop + bias + log-softmax; one wave per node
// ---------------------------------------------------------------------------
__global__ __launch_bounds__(256) void gather_kernel(const int* __restrict__ offsets,
                                                     const int2* __restrict__ pairs,
                                                     const float* __restrict__ xw,
                                                     const float* __restrict__ gso2,
                                                     const float* __restrict__ b,
                                                     float* __restrict__ out, int n) {
    int lane = threadIdx.x & 63;
    int node = blockIdx.x * 4 + (threadIdx.x >> 6);
    if (node >= n) return;
    int lo = offsets[node], hi = offsets[node + 1];
    float v = gso2[node] * xw[(size_t)node * DOUT + lane] + 2.0f * b[lane];
    int i = lo;
    for (; i + 4 <= hi; i += 4) {
        int2 p0 = pairs[i], p1 = pairs[i + 1], p2 = pairs[i + 2], p3 = pairs[i + 3];
        float a0 = xw[(size_t)p0.x * DOUT + lane];
        float a1 = xw[(size_t)p1.x * DOUT + lane];
        float a2 = xw[(size_t)p2.x * DOUT + lane];
        float a3 = xw[(size_t)p3.x * DOUT + lane];
        v += __int_as_float(p0.y) * a0 + __int_as_float(p1.y) * a1
           + __int_as_float(p2.y) * a2 + __int_as_float(p3.y) * a3;
    }
    for (; i < hi; ++i) {
        int2 p = pairs[i];
        v += __int_as_float(p.y) * xw[(size_t)p.x * DOUT + lane];
    }
    float m = v;
#pragma unroll
    for (int d = 1; d < 64; d <<= 1) m = fmaxf(m, __shfl_xor(m, d));
    float s = expf(v - m);
#pragma unroll
    for (int d = 1; d < 64; d <<= 1) s += __shfl_xor(s, d);
    out[(size_t)node * DOUT + lane] = v - m - logf(s);
}

// ---------------------------------------------------------------------------
extern "C" void kernel_launch(void* const* d_in, const int* in_sizes, int n_in,
                              void* d_out, int out_size, void* d_ws, size_t ws_size,
                              hipStream_t stream) {
    const float* x     = (const float*)d_in[0];
    const int*   ei    = (const int*)d_in[1];
    const float* diags = (const float*)d_in[3];
    const float* W     = (const float*)d_in[4];
    const float* b     = (const float*)d_in[5];
    const float* m1    = (const float*)d_in[6];
    const float* m2    = (const float*)d_in[7];
    const float* m3    = (const float*)d_in[8];
    const float* e1    = (const float*)d_in[9];
    const float* e2    = (const float*)d_in[10];
    const float* e3    = (const float*)d_in[11];
    float* out = (float*)d_out;

    const int n = in_sizes[3];          // 100000
    const int e_cnt = in_sizes[1] / 2;  // 1600000
    const int nb = (n + 1023) / 1024;   // scan blocks

    char* ws = (char*)d_ws;
    float* Wo       = (float*)ws;                       // 8K floats
    float* d_e2m    = (float*)(ws + 32768);             // n
    float* d_e3p    = d_e2m + n;                        // n
    float* gso2     = d_e3p + n;                        // n
    float* xw       = gso2 + n;                         // n*64
    int*   counts   = (int*)(xw + (size_t)n * DOUT);    // n
    int*   offsets  = counts + n;                       // n+4
    int*   cursors  = offsets + n + 4;                  // n
    int*   partials = cursors + n;                      // 128
    int*   blk_off  = partials + 128;                   // 128
    uintptr_t pp = ((uintptr_t)(blk_off + 128) + 15) & ~(uintptr_t)15;
    int2*  pairs    = (int2*)pp;                        // e_cnt

    hipMemsetAsync(counts, 0, (size_t)n * sizeof(int), stream);

    bjorck_kernel<<<1, 256, 0, stream>>>(W, Wo);
    node_prep<<<(n + 255) / 256, 256, 0, stream>>>(diags, m1, m2, m3, e1, e2, e3,
                                                   d_e2m, d_e3p, gso2, n);
    xw_kernel<<<(n + XN - 1) / XN, 256, 0, stream>>>(x, Wo, xw, n);
    hist_kernel<<<(e_cnt + 255) / 256, 256, 0, stream>>>(ei, counts, e_cnt);
    scan_partial<<<nb, 256, 0, stream>>>(counts, partials, n);
    scan_mid<<<1, 128, 0, stream>>>(partials, blk_off, nb);
    scan_write<<<nb, 256, 0, stream>>>(counts, blk_off, offsets, cursors, n, e_cnt);
    reorder_kernel<<<(e_cnt + 255) / 256, 256, 0, stream>>>(ei, d_e2m, d_e3p,
                                                            cursors, pairs, e_cnt);
    gather_kernel<<<(n + 3) / 4, 256, 0, stream>>>(offsets, pairs, xw, gso2, b,
                                                   out, n);
}

// Round 7
// 373.023 us; speedup vs baseline: 1.1141x; 1.1069x over previous
//
#include <hip/hip_runtime.h>
#include <math.h>

#define DIN 128
#define DOUT 64
#define GR 68               // 64x64 LDS row stride (floats), 16B-aligned rows

__device__ __forceinline__ float safe_pow(float d, float e) {
    float p = powf(d, e);
    return isinf(p) ? 0.0f : p;
}

__device__ __forceinline__ float dot4(float4 a, float4 b) {
    return a.x * b.x + a.y * b.y + a.z * b.z + a.w * b.w;
}

// ---------------------------------------------------------------------------
// 64x64 LDS matmul, 512 threads (8 waves = 2/SIMD for latency hiding).
// Thread t -> C rows {ti, ti+1} (ti=(t>>4)*2), cols {m,m+16,m+32,m+48} (m=t&15).
// REQUIRES B symmetric (rows read as cols). All LDS addresses compile-time
// affine in the unrolled k-loop (round-5 lesson). B-row reads 2-way bank
// aliased max (free); C scalar stores 2-way max.
// ---------------------------------------------------------------------------
__device__ __forceinline__ void mm512(const float* __restrict__ A,
                                      const float* __restrict__ Bs,
                                      float* __restrict__ C, int t) {
    int ti = (t >> 4) * 2, m = t & 15;
    float acc[2][4] = {};
#pragma unroll
    for (int k4 = 0; k4 < 16; ++k4) {
        float4 a[2], bb[4];
#pragma unroll
        for (int r = 0; r < 2; ++r) a[r] = *(const float4*)&A[(ti + r) * GR + k4 * 4];
#pragma unroll
        for (int c = 0; c < 4; ++c) bb[c] = *(const float4*)&Bs[(m + c * 16) * GR + k4 * 4];
#pragma unroll
        for (int r = 0; r < 2; ++r)
#pragma unroll
            for (int c = 0; c < 4; ++c) acc[r][c] += dot4(a[r], bb[c]);
    }
#pragma unroll
    for (int r = 0; r < 2; ++r)
#pragma unroll
        for (int c = 0; c < 4; ++c) C[(ti + r) * GR + m + c * 16] = acc[r][c];
}

// C1 = A1 @ Bs and C2 = A2 @ Bs in one pass (shared Bs reads).
__device__ __forceinline__ void mm512_dual(const float* __restrict__ A1,
                                           const float* __restrict__ A2,
                                           const float* __restrict__ Bs,
                                           float* __restrict__ C1,
                                           float* __restrict__ C2, int t) {
    int ti = (t >> 4) * 2, m = t & 15;
    float acc1[2][4] = {}, acc2[2][4] = {};
#pragma unroll
    for (int k4 = 0; k4 < 16; ++k4) {
        float4 bb[4];
#pragma unroll
        for (int c = 0; c < 4; ++c) bb[c] = *(const float4*)&Bs[(m + c * 16) * GR + k4 * 4];
#pragma unroll
        for (int r = 0; r < 2; ++r) {
            float4 a = *(const float4*)&A1[(ti + r) * GR + k4 * 4];
#pragma unroll
            for (int c = 0; c < 4; ++c) acc1[r][c] += dot4(a, bb[c]);
        }
#pragma unroll
        for (int r = 0; r < 2; ++r) {
            float4 a = *(const float4*)&A2[(ti + r) * GR + k4 * 4];
#pragma unroll
            for (int c = 0; c < 4; ++c) acc2[r][c] += dot4(a, bb[c]);
        }
    }
#pragma unroll
    for (int r = 0; r < 2; ++r)
#pragma unroll
        for (int c = 0; c < 4; ++c) {
            C1[(ti + r) * GR + m + c * 16] = acc1[r][c];
            C2[(ti + r) * GR + m + c * 16] = acc2[r][c];
        }
}

// ---------------------------------------------------------------------------
// Bjorck stage 1: G = W W^T; H = G^2; H2 = G^4. Writes gG, gH2 (64x64, row
// stride 64) to workspace.
// ---------------------------------------------------------------------------
__global__ __launch_bounds__(512) void k1_gram(const float* __restrict__ W,
                                               float* __restrict__ gG,
                                               float* __restrict__ gH2) {
    __shared__ __align__(16) float Gs[DOUT * GR];
    __shared__ __align__(16) float T1[DOUT * GR];
    __shared__ __align__(16) float T2[DOUT * GR];
    int t = threadIdx.x;
    {
        int ti = (t >> 4) * 2, m = t & 15;
        float acc[2][4] = {};
        for (int k4 = 0; k4 < DIN / 4; ++k4) {
            float4 a[2], bb[4];
#pragma unroll
            for (int r = 0; r < 2; ++r) a[r] = *(const float4*)&W[(ti + r) * DIN + k4 * 4];
#pragma unroll
            for (int c = 0; c < 4; ++c) bb[c] = *(const float4*)&W[(m + c * 16) * DIN + k4 * 4];
#pragma unroll
            for (int r = 0; r < 2; ++r)
#pragma unroll
                for (int c = 0; c < 4; ++c) acc[r][c] += dot4(a[r], bb[c]);
        }
#pragma unroll
        for (int r = 0; r < 2; ++r)
#pragma unroll
            for (int c = 0; c < 4; ++c) Gs[(ti + r) * GR + m + c * 16] = acc[r][c];
    }
    __syncthreads();
    mm512(Gs, Gs, T1, t);     // H = G^2
    __syncthreads();
    mm512(T1, T1, T2, t);     // H2 = G^4
    __syncthreads();
    for (int q = t; q < DOUT * 16; q += 512) {
        int row = q >> 4, c4 = q & 15;
        *(float4*)&gG[row * 64 + c4 * 4]  = *(const float4*)&Gs[row * GR + c4 * 4];
        *(float4*)&gH2[row * 64 + c4 * 4] = *(const float4*)&T2[row * GR + c4 * 4];
    }
}

// ---------------------------------------------------------------------------
// Bjorck stage 2: squared-operator power iteration on H2 (= G^4), one wave.
// Trace-scaled, 8 raw iters (no normalization in chain) + Rayleigh quotient.
// Writes gSc[0]=sc=1/(1.1 sigma), gSc[1]=rs=1/(1.21 sigma^2).
// ---------------------------------------------------------------------------
__global__ __launch_bounds__(64) void k2_power(const float* __restrict__ gH2,
                                               float* __restrict__ gSc) {
    int t = threadIdx.x;
    float tr = gH2[t * 65];                 // diag element, row t col t
#pragma unroll
    for (int d = 1; d < 64; d <<= 1) tr += __shfl_xor(tr, d);
    float inv_tr = 1.0f / tr;
    float4 g4[16];
#pragma unroll
    for (int j4 = 0; j4 < 16; ++j4) {
        float4 v = *(const float4*)&gH2[t * 64 + j4 * 4];
        v.x *= inv_tr; v.y *= inv_tr; v.z *= inv_tr; v.w *= inv_tr;
        g4[j4] = v;
    }
    unsigned h = (unsigned)t * 2654435761u;
    float xv = 0.5f + (float)((h >> 17) & 0x7fff) * (1.0f / 32768.0f);
    float yv = 0.f;
    for (int it = 0; it < 8; ++it) {
        float p0 = 0.f, p1 = 0.f, p2 = 0.f, p3 = 0.f;
#pragma unroll
        for (int j4 = 0; j4 < 16; ++j4) {
            float4 xx;
            xx.x = __shfl(xv, j4 * 4 + 0);
            xx.y = __shfl(xv, j4 * 4 + 1);
            xx.z = __shfl(xv, j4 * 4 + 2);
            xx.w = __shfl(xv, j4 * 4 + 3);
            float dd = dot4(g4[j4], xx);
            if (j4 < 4) p0 += dd; else if (j4 < 8) p1 += dd;
            else if (j4 < 12) p2 += dd; else p3 += dd;
        }
        yv = (p0 + p1) + (p2 + p3);
        if (it < 7) xv = yv;
    }
    float num = xv * yv, den = xv * xv;
#pragma unroll
    for (int d = 1; d < 64; d <<= 1) {
        num += __shfl_xor(num, d);
        den += __shfl_xor(den, d);
    }
    if (t == 0) {
        float lam_h2 = tr * num / den;        // = sigma^8
        float sig = powf(lam_h2, 0.125f);
        gSc[0] = 1.0f / (1.1f * sig);
        gSc[1] = 1.0f / (1.21f * sig * sig);
    }
}

// ---------------------------------------------------------------------------
// Bjorck stage 3: A0 = rs*G; 5x { B=1.5I-0.5A; P<-P@B; A<-(A@B)@B }.
// Writes final P (64x64, stride 64) to gP.
// ---------------------------------------------------------------------------
__global__ __launch_bounds__(512) void k3_iter(const float* __restrict__ gG,
                                               const float* __restrict__ gSc,
                                               float* __restrict__ gP) {
    __shared__ __align__(16) float A0s[DOUT * GR];
    __shared__ __align__(16) float A1s[DOUT * GR];
    __shared__ __align__(16) float P0s[DOUT * GR];
    __shared__ __align__(16) float P1s[DOUT * GR];
    __shared__ __align__(16) float Bm[DOUT * GR];
    int t = threadIdx.x;
    float rs = gSc[1];
    for (int q = t; q < DOUT * 16; q += 512) {
        int row = q >> 4, c4 = q & 15;
        float4 v = *(const float4*)&gG[row * 64 + c4 * 4];
        v.x *= rs; v.y *= rs; v.z *= rs; v.w *= rs;
        *(float4*)&A0s[row * GR + c4 * 4] = v;
    }
    __syncthreads();

    float *Ac = A0s, *Pc = P0s, *s1 = A1s, *s2 = P1s;
    for (int it = 0; it < 5; ++it) {
        for (int q = t; q < DOUT * 64; q += 512) {
            int i = q >> 6, j = q & 63;
            float v = (i == j ? 1.5f : 0.0f) - 0.5f * Ac[i * GR + j];
            Bm[i * GR + j] = v;
            if (it == 0) Pc[i * GR + j] = v;
        }
        __syncthreads();
        if (it == 0) {
            mm512(Ac, Bm, s1, t);                 // T = A@B
            __syncthreads();
            mm512(s1, Bm, s2, t);                 // Anew = T@B
            __syncthreads();
            float* na = s2; s2 = s1; s1 = Ac; Ac = na;
        } else if (it < 4) {
            mm512_dual(Pc, Ac, Bm, s1, s2, t);    // Pnew = s1, T = s2
            __syncthreads();
            mm512(s2, Bm, Pc, t);                 // Anew into dead old-P
            __syncthreads();
            float* na = Pc; float* np = s1; s1 = Ac; Ac = na; Pc = np;
        } else {
            mm512(Pc, Bm, s1, t);                 // P final
            __syncthreads();
        }
    }
    const float* Pf = s1;
    for (int q = t; q < DOUT * 16; q += 512) {
        int row = q >> 4, c4 = q & 15;
        *(float4*)&gP[row * 64 + c4 * 4] = *(const float4*)&Pf[row * GR + c4 * 4];
    }
}

// ---------------------------------------------------------------------------
// Bjorck stage 4: Wo = sc * P @ W  (64 x 128). 512 threads, 2 rows x 8 cols.
// ---------------------------------------------------------------------------
__global__ __launch_bounds__(512) void k4_wo(const float* __restrict__ W,
                                             const float* __restrict__ gP,
                                             const float* __restrict__ gSc,
                                             float* __restrict__ Wo) {
    __shared__ __align__(16) float Ps[DOUT * GR];
    int t = threadIdx.x;
    for (int q = t; q < DOUT * 16; q += 512) {
        int row = q >> 4, c4 = q & 15;
        *(float4*)&Ps[row * GR + c4 * 4] = *(const float4*)&gP[row * 64 + c4 * 4];
    }
    __syncthreads();
    float sc = gSc[0];
    int i0 = (t >> 4) * 2;
    int k0 = (t & 15) * 8;
    float4 acc0[2] = {}, acc1[2] = {};
    for (int j = 0; j < 64; ++j) {
        float4 w0 = *(const float4*)&W[j * DIN + k0];
        float4 w1 = *(const float4*)&W[j * DIN + k0 + 4];
#pragma unroll
        for (int r = 0; r < 2; ++r) {
            float pv = Ps[(i0 + r) * GR + j];
            acc0[r].x += pv * w0.x; acc0[r].y += pv * w0.y;
            acc0[r].z += pv * w0.z; acc0[r].w += pv * w0.w;
            acc1[r].x += pv * w1.x; acc1[r].y += pv * w1.y;
            acc1[r].z += pv * w1.z; acc1[r].w += pv * w1.w;
        }
    }
#pragma unroll
    for (int r = 0; r < 2; ++r) {
        float4 o0 = make_float4(sc * acc0[r].x, sc * acc0[r].y, sc * acc0[r].z, sc * acc0[r].w);
        float4 o1 = make_float4(sc * acc1[r].x, sc * acc1[r].y, sc * acc1[r].z, sc * acc1[r].w);
        *(float4*)&Wo[(i0 + r) * DIN + k0] = o0;
        *(float4*)&Wo[(i0 + r) * DIN + k0 + 4] = o1;
    }
}

// ---------------------------------------------------------------------------
// per-node prep
// ---------------------------------------------------------------------------
__global__ void node_prep(const float* __restrict__ diags,
                          const float* m1, const float* m2, const float* m3,
                          const float* e1, const float* e2, const float* e3,
                          float* __restrict__ d_e2m, float* __restrict__ d_e3p,
                          float* __restrict__ gso2, int n) {
    int i = blockIdx.x * blockDim.x + threadIdx.x;
    if (i >= n) return;
    float d = diags[i];
    float p1 = safe_pow(d, e1[0]);
    float p2 = safe_pow(d, e2[0]);
    float p3 = safe_pow(d, e3[0]);
    float vm2 = m2[0];
    d_e2m[i] = vm2 * p2;
    d_e3p[i] = p3;
    gso2[i] = m1[0] * p1 + vm2 * p2 * p3 + m3[0];
}

// ---------------------------------------------------------------------------
// xw = x @ Wo^T — register-tiled GEMM (64-node tile, 4x4 per thread)
// ---------------------------------------------------------------------------
#define XN 64
#define XS 132
__global__ __launch_bounds__(256) void xw_kernel(const float* __restrict__ x,
                                                 const float* __restrict__ Wo,
                                                 float* __restrict__ xw, int n) {
    __shared__ __align__(16) float xs[XN * XS];
    __shared__ __align__(16) float ws[DOUT * XS];
    int t = threadIdx.x;
    int base = blockIdx.x * XN;
    for (int f = t; f < DOUT * (DIN / 4); f += 256) {
        int r = f >> 5, c = f & 31;
        *(float4*)&ws[r * XS + c * 4] = *(const float4*)&Wo[r * DIN + c * 4];
    }
    for (int f = t; f < XN * (DIN / 4); f += 256) {
        int r = f >> 5, c = f & 31;
        int node = base + r;
        float4 v = make_float4(0.f, 0.f, 0.f, 0.f);
        if (node < n) v = *(const float4*)&x[(size_t)node * DIN + c * 4];
        *(float4*)&xs[r * XS + c * 4] = v;
    }
    __syncthreads();
    int tn = t >> 4;
    int td = t & 15;
    float acc[4][4] = {};
#pragma unroll 2
    for (int k4 = 0; k4 < DIN / 4; ++k4) {
        float4 a[4], w[4];
#pragma unroll
        for (int r = 0; r < 4; ++r) a[r] = *(const float4*)&xs[(tn * 4 + r) * XS + k4 * 4];
#pragma unroll
        for (int c = 0; c < 4; ++c) w[c] = *(const float4*)&ws[(td + c * 16) * XS + k4 * 4];
#pragma unroll
        for (int r = 0; r < 4; ++r)
#pragma unroll
            for (int c = 0; c < 4; ++c) acc[r][c] += dot4(a[r], w[c]);
    }
#pragma unroll
    for (int r = 0; r < 4; ++r) {
        int node = base + tn * 4 + r;
        if (node >= n) break;
#pragma unroll
        for (int c = 0; c < 4; ++c)
            xw[(size_t)node * DOUT + td + c * 16] = acc[r][c];
    }
}

// ---------------------------------------------------------------------------
// histogram of destination column
// ---------------------------------------------------------------------------
__global__ __launch_bounds__(256) void hist_kernel(const int* __restrict__ ei,
                                                   int* __restrict__ counts, int e_cnt) {
    int e = blockIdx.x * blockDim.x + threadIdx.x;
    if (e >= e_cnt) return;
    atomicAdd(&counts[ei[e_cnt + e]], 1);
}

// ---------------------------------------------------------------------------
// 3-phase scan
// ---------------------------------------------------------------------------
__global__ __launch_bounds__(256) void scan_partial(const int* __restrict__ counts,
                                                    int* __restrict__ partials, int n) {
    __shared__ int wsum[4];
    int b = blockIdx.x, t = threadIdx.x;
    int base = b * 1024 + t * 4;
    int s = 0;
    if (base + 4 <= n) {
        int4 v = *(const int4*)&counts[base];
        s = v.x + v.y + v.z + v.w;
    } else {
        for (int i = base; i < n; ++i) s += counts[i];
    }
#pragma unroll
    for (int d = 1; d < 64; d <<= 1) s += __shfl_xor(s, d);
    if ((t & 63) == 0) wsum[t >> 6] = s;
    __syncthreads();
    if (t == 0) partials[b] = wsum[0] + wsum[1] + wsum[2] + wsum[3];
}

__global__ __launch_bounds__(128) void scan_mid(const int* __restrict__ partials,
                                                int* __restrict__ blk_off, int nb) {
    __shared__ int sh[128];
    int t = threadIdx.x;
    int v = (t < nb) ? partials[t] : 0;
    sh[t] = v;
    __syncthreads();
    for (int d = 1; d < 128; d <<= 1) {
        int u = (t >= d) ? sh[t - d] : 0;
        __syncthreads();
        sh[t] += u;
        __syncthreads();
    }
    if (t < nb) blk_off[t] = sh[t] - v;
}

__global__ __launch_bounds__(256) void scan_write(const int* __restrict__ counts,
                                                  const int* __restrict__ blk_off,
                                                  int* __restrict__ offsets,
                                                  int* __restrict__ cursors,
                                                  int n, int e_cnt) {
    __shared__ int sh[256];
    int b = blockIdx.x, t = threadIdx.x;
    int base = b * 1024 + t * 4;
    int4 v = make_int4(0, 0, 0, 0);
    bool full = (base + 4 <= n);
    if (full) {
        v = *(const int4*)&counts[base];
    } else {
        int* vv = &v.x;
        for (int i = 0; i < 4; ++i) vv[i] = (base + i < n) ? counts[base + i] : 0;
    }
    int s = v.x + v.y + v.z + v.w;
    sh[t] = s;
    __syncthreads();
    for (int d = 1; d < 256; d <<= 1) {
        int u = (t >= d) ? sh[t - d] : 0;
        __syncthreads();
        sh[t] += u;
        __syncthreads();
    }
    int run = blk_off[b] + sh[t] - s;
    int4 o;
    o.x = run;
    o.y = run + v.x;
    o.z = o.y + v.y;
    o.w = o.z + v.z;
    if (full) {
        *(int4*)&offsets[base] = o;
        *(int4*)&cursors[base] = o;
    } else {
        int* oo = &o.x;
        for (int i = 0; i < 4; ++i)
            if (base + i < n) { offsets[base + i] = oo[i]; cursors[base + i] = oo[i]; }
    }
    if (b == 0 && t == 0) offsets[n] = e_cnt;
}

// ---------------------------------------------------------------------------
// reorder edges into CSR-by-col as interleaved (src, weight) int2 pairs
// ---------------------------------------------------------------------------
__global__ __launch_bounds__(256) void reorder_kernel(const int* __restrict__ ei,
                                                      const float* __restrict__ d_e2m,
                                                      const float* __restrict__ d_e3p,
                                                      int* __restrict__ cursors,
                                                      int2* __restrict__ pairs, int e_cnt) {
    int e = blockIdx.x * blockDim.x + threadIdx.x;
    if (e >= e_cnt) return;
    int row = ei[e];
    int col = ei[e_cnt + e];
    int pos = atomicAdd(&cursors[col], 1);
    int2 p;
    p.x = row;
    p.y = __float_as_int(d_e2m[row] * d_e3p[col]);
    pairs[pos] = p;
}

// ---------------------------------------------------------------------------
// fused gather + self-loop + bias + log-softmax; one wave per node
// ---------------------------------------------------------------------------
__global__ __launch_bounds__(256) void gather_kernel(const int* __restrict__ offsets,
                                                     const int2* __restrict__ pairs,
                                                     const float* __restrict__ xw,
                                                     const float* __restrict__ gso2,
                                                     const float* __restrict__ b,
                                                     float* __restrict__ out, int n) {
    int lane = threadIdx.x & 63;
    int node = blockIdx.x * 4 + (threadIdx.x >> 6);
    if (node >= n) return;
    int lo = offsets[node], hi = offsets[node + 1];
    float v = gso2[node] * xw[(size_t)node * DOUT + lane] + 2.0f * b[lane];
    int i = lo;
    for (; i + 4 <= hi; i += 4) {
        int2 p0 = pairs[i], p1 = pairs[i + 1], p2 = pairs[i + 2], p3 = pairs[i + 3];
        float a0 = xw[(size_t)p0.x * DOUT + lane];
        float a1 = xw[(size_t)p1.x * DOUT + lane];
        float a2 = xw[(size_t)p2.x * DOUT + lane];
        float a3 = xw[(size_t)p3.x * DOUT + lane];
        v += __int_as_float(p0.y) * a0 + __int_as_float(p1.y) * a1
           + __int_as_float(p2.y) * a2 + __int_as_float(p3.y) * a3;
    }
    for (; i < hi; ++i) {
        int2 p = pairs[i];
        v += __int_as_float(p.y) * xw[(size_t)p.x * DOUT + lane];
    }
    float m = v;
#pragma unroll
    for (int d = 1; d < 64; d <<= 1) m = fmaxf(m, __shfl_xor(m, d));
    float s = expf(v - m);
#pragma unroll
    for (int d = 1; d < 64; d <<= 1) s += __shfl_xor(s, d);
    out[(size_t)node * DOUT + lane] = v - m - logf(s);
}

// ---------------------------------------------------------------------------
extern "C" void kernel_launch(void* const* d_in, const int* in_sizes, int n_in,
                              void* d_out, int out_size, void* d_ws, size_t ws_size,
                              hipStream_t stream) {
    const float* x     = (const float*)d_in[0];
    const int*   ei    = (const int*)d_in[1];
    const float* diags = (const float*)d_in[3];
    const float* W     = (const float*)d_in[4];
    const float* b     = (const float*)d_in[5];
    const float* m1    = (const float*)d_in[6];
    const float* m2    = (const float*)d_in[7];
    const float* m3    = (const float*)d_in[8];
    const float* e1    = (const float*)d_in[9];
    const float* e2    = (const float*)d_in[10];
    const float* e3    = (const float*)d_in[11];
    float* out = (float*)d_out;

    const int n = in_sizes[3];          // 100000
    const int e_cnt = in_sizes[1] / 2;  // 1600000
    const int nb = (n + 1023) / 1024;   // scan blocks

    char* ws = (char*)d_ws;
    float* Wo       = (float*)ws;                       // 8K floats
    float* d_e2m    = (float*)(ws + 32768);             // n
    float* d_e3p    = d_e2m + n;                        // n
    float* gso2     = d_e3p + n;                        // n
    float* xw       = gso2 + n;                         // n*64
    int*   counts   = (int*)(xw + (size_t)n * DOUT);    // n
    int*   offsets  = counts + n;                       // n+4
    int*   cursors  = offsets + n + 4;                  // n
    int*   partials = cursors + n;                      // 128
    int*   blk_off  = partials + 128;                   // 128
    uintptr_t pp = ((uintptr_t)(blk_off + 128) + 15) & ~(uintptr_t)15;
    int2*  pairs    = (int2*)pp;                        // e_cnt
    float* gG       = (float*)(pairs + e_cnt);          // 4096
    float* gH2      = gG + 4096;                        // 4096
    float* gP       = gH2 + 4096;                       // 4096
    float* gSc      = gP + 4096;                        // 2

    hipMemsetAsync(counts, 0, (size_t)n * sizeof(int), stream);

    k1_gram<<<1, 512, 0, stream>>>(W, gG, gH2);
    k2_power<<<1, 64, 0, stream>>>(gH2, gSc);
    k3_iter<<<1, 512, 0, stream>>>(gG, gSc, gP);
    k4_wo<<<1, 512, 0, stream>>>(W, gP, gSc, Wo);
    node_prep<<<(n + 255) / 256, 256, 0, stream>>>(diags, m1, m2, m3, e1, e2, e3,
                                                   d_e2m, d_e3p, gso2, n);
    xw_kernel<<<(n + XN - 1) / XN, 256, 0, stream>>>(x, Wo, xw, n);
    hist_kernel<<<(e_cnt + 255) / 256, 256, 0, stream>>>(ei, counts, e_cnt);
    scan_partial<<<nb, 256, 0, stream>>>(counts, partials, n);
    scan_mid<<<1, 128, 0, stream>>>(partials, blk_off, nb);
    scan_write<<<nb, 256, 0, stream>>>(counts, blk_off, offsets, cursors, n, e_cnt);
    reorder_kernel<<<(e_cnt + 255) / 256, 256, 0, stream>>>(ei, d_e2m, d_e3p,
                                                            cursors, pairs, e_cnt);
    gather_kernel<<<(n + 3) / 4, 256, 0, stream>>>(offsets, pairs, xw, gso2, b,
                                                   out, n);
}

// Round 8
// 289.299 us; speedup vs baseline: 1.4365x; 1.2894x over previous
//
#include <hip/hip_runtime.h>
#include <math.h>

#define DIN 128
#define DOUT 64
#define GR 68               // 64x64 LDS row stride (floats), 16B-aligned rows

#define NBLK 64             // binning blocks
#define BK_SHIFT 7          // 128 cols per bucket
#define BK_COLS 128
#define NBK_STRIDE 1024     // blk_hist row stride (buckets padded)
#define CCAP 4096           // max edges per bucket staged in LDS (mean ~2046)

__device__ __forceinline__ float safe_pow(float d, float e) {
    float p = powf(d, e);
    return isinf(p) ? 0.0f : p;
}

__device__ __forceinline__ float dot4(float4 a, float4 b) {
    return a.x * b.x + a.y * b.y + a.z * b.z + a.w * b.w;
}

// ---------------------------------------------------------------------------
// 64x64 LDS matmul, 512 threads (8 waves = 2/SIMD). B must be symmetric.
// ---------------------------------------------------------------------------
__device__ __forceinline__ void mm512(const float* __restrict__ A,
                                      const float* __restrict__ Bs,
                                      float* __restrict__ C, int t) {
    int ti = (t >> 4) * 2, m = t & 15;
    float acc[2][4] = {};
#pragma unroll
    for (int k4 = 0; k4 < 16; ++k4) {
        float4 a[2], bb[4];
#pragma unroll
        for (int r = 0; r < 2; ++r) a[r] = *(const float4*)&A[(ti + r) * GR + k4 * 4];
#pragma unroll
        for (int c = 0; c < 4; ++c) bb[c] = *(const float4*)&Bs[(m + c * 16) * GR + k4 * 4];
#pragma unroll
        for (int r = 0; r < 2; ++r)
#pragma unroll
            for (int c = 0; c < 4; ++c) acc[r][c] += dot4(a[r], bb[c]);
    }
#pragma unroll
    for (int r = 0; r < 2; ++r)
#pragma unroll
        for (int c = 0; c < 4; ++c) C[(ti + r) * GR + m + c * 16] = acc[r][c];
}

__device__ __forceinline__ void mm512_dual(const float* __restrict__ A1,
                                           const float* __restrict__ A2,
                                           const float* __restrict__ Bs,
                                           float* __restrict__ C1,
                                           float* __restrict__ C2, int t) {
    int ti = (t >> 4) * 2, m = t & 15;
    float acc1[2][4] = {}, acc2[2][4] = {};
#pragma unroll
    for (int k4 = 0; k4 < 16; ++k4) {
        float4 bb[4];
#pragma unroll
        for (int c = 0; c < 4; ++c) bb[c] = *(const float4*)&Bs[(m + c * 16) * GR + k4 * 4];
#pragma unroll
        for (int r = 0; r < 2; ++r) {
            float4 a = *(const float4*)&A1[(ti + r) * GR + k4 * 4];
#pragma unroll
            for (int c = 0; c < 4; ++c) acc1[r][c] += dot4(a, bb[c]);
        }
#pragma unroll
        for (int r = 0; r < 2; ++r) {
            float4 a = *(const float4*)&A2[(ti + r) * GR + k4 * 4];
#pragma unroll
            for (int c = 0; c < 4; ++c) acc2[r][c] += dot4(a, bb[c]);
        }
    }
#pragma unroll
    for (int r = 0; r < 2; ++r)
#pragma unroll
        for (int c = 0; c < 4; ++c) {
            C1[(ti + r) * GR + m + c * 16] = acc1[r][c];
            C2[(ti + r) * GR + m + c * 16] = acc2[r][c];
        }
}

// ---------------------------------------------------------------------------
// Bjorck stage 1: G = W W^T; H2 = G^4.
// ---------------------------------------------------------------------------
__global__ __launch_bounds__(512) void k1_gram(const float* __restrict__ W,
                                               float* __restrict__ gG,
                                               float* __restrict__ gH2) {
    __shared__ __align__(16) float Gs[DOUT * GR];
    __shared__ __align__(16) float T1[DOUT * GR];
    __shared__ __align__(16) float T2[DOUT * GR];
    int t = threadIdx.x;
    {
        int ti = (t >> 4) * 2, m = t & 15;
        float acc[2][4] = {};
        for (int k4 = 0; k4 < DIN / 4; ++k4) {
            float4 a[2], bb[4];
#pragma unroll
            for (int r = 0; r < 2; ++r) a[r] = *(const float4*)&W[(ti + r) * DIN + k4 * 4];
#pragma unroll
            for (int c = 0; c < 4; ++c) bb[c] = *(const float4*)&W[(m + c * 16) * DIN + k4 * 4];
#pragma unroll
            for (int r = 0; r < 2; ++r)
#pragma unroll
                for (int c = 0; c < 4; ++c) acc[r][c] += dot4(a[r], bb[c]);
        }
#pragma unroll
        for (int r = 0; r < 2; ++r)
#pragma unroll
            for (int c = 0; c < 4; ++c) Gs[(ti + r) * GR + m + c * 16] = acc[r][c];
    }
    __syncthreads();
    mm512(Gs, Gs, T1, t);     // H = G^2
    __syncthreads();
    mm512(T1, T1, T2, t);     // H2 = G^4
    __syncthreads();
    for (int q = t; q < DOUT * 16; q += 512) {
        int row = q >> 4, c4 = q & 15;
        *(float4*)&gG[row * 64 + c4 * 4]  = *(const float4*)&Gs[row * GR + c4 * 4];
        *(float4*)&gH2[row * 64 + c4 * 4] = *(const float4*)&T2[row * GR + c4 * 4];
    }
}

// ---------------------------------------------------------------------------
// Bjorck stage 2: power iteration on H2 (trace-scaled, raw chain + Rayleigh).
// ---------------------------------------------------------------------------
__global__ __launch_bounds__(64) void k2_power(const float* __restrict__ gH2,
                                               float* __restrict__ gSc) {
    int t = threadIdx.x;
    float tr = gH2[t * 65];
#pragma unroll
    for (int d = 1; d < 64; d <<= 1) tr += __shfl_xor(tr, d);
    float inv_tr = 1.0f / tr;
    float4 g4[16];
#pragma unroll
    for (int j4 = 0; j4 < 16; ++j4) {
        float4 v = *(const float4*)&gH2[t * 64 + j4 * 4];
        v.x *= inv_tr; v.y *= inv_tr; v.z *= inv_tr; v.w *= inv_tr;
        g4[j4] = v;
    }
    unsigned h = (unsigned)t * 2654435761u;
    float xv = 0.5f + (float)((h >> 17) & 0x7fff) * (1.0f / 32768.0f);
    float yv = 0.f;
    for (int it = 0; it < 8; ++it) {
        float p0 = 0.f, p1 = 0.f, p2 = 0.f, p3 = 0.f;
#pragma unroll
        for (int j4 = 0; j4 < 16; ++j4) {
            float4 xx;
            xx.x = __shfl(xv, j4 * 4 + 0);
            xx.y = __shfl(xv, j4 * 4 + 1);
            xx.z = __shfl(xv, j4 * 4 + 2);
            xx.w = __shfl(xv, j4 * 4 + 3);
            float dd = dot4(g4[j4], xx);
            if (j4 < 4) p0 += dd; else if (j4 < 8) p1 += dd;
            else if (j4 < 12) p2 += dd; else p3 += dd;
        }
        yv = (p0 + p1) + (p2 + p3);
        if (it < 7) xv = yv;
    }
    float num = xv * yv, den = xv * xv;
#pragma unroll
    for (int d = 1; d < 64; d <<= 1) {
        num += __shfl_xor(num, d);
        den += __shfl_xor(den, d);
    }
    if (t == 0) {
        float lam_h2 = tr * num / den;        // = sigma^8
        float sig = powf(lam_h2, 0.125f);
        gSc[0] = 1.0f / (1.1f * sig);
        gSc[1] = 1.0f / (1.21f * sig * sig);
    }
}

// ---------------------------------------------------------------------------
// Bjorck stage 3: 5 Gram-domain iterations.
// ---------------------------------------------------------------------------
__global__ __launch_bounds__(512) void k3_iter(const float* __restrict__ gG,
                                               const float* __restrict__ gSc,
                                               float* __restrict__ gP) {
    __shared__ __align__(16) float A0s[DOUT * GR];
    __shared__ __align__(16) float A1s[DOUT * GR];
    __shared__ __align__(16) float P0s[DOUT * GR];
    __shared__ __align__(16) float P1s[DOUT * GR];
    __shared__ __align__(16) float Bm[DOUT * GR];
    int t = threadIdx.x;
    float rs = gSc[1];
    for (int q = t; q < DOUT * 16; q += 512) {
        int row = q >> 4, c4 = q & 15;
        float4 v = *(const float4*)&gG[row * 64 + c4 * 4];
        v.x *= rs; v.y *= rs; v.z *= rs; v.w *= rs;
        *(float4*)&A0s[row * GR + c4 * 4] = v;
    }
    __syncthreads();

    float *Ac = A0s, *Pc = P0s, *s1 = A1s, *s2 = P1s;
    for (int it = 0; it < 5; ++it) {
        for (int q = t; q < DOUT * 64; q += 512) {
            int i = q >> 6, j = q & 63;
            float v = (i == j ? 1.5f : 0.0f) - 0.5f * Ac[i * GR + j];
            Bm[i * GR + j] = v;
            if (it == 0) Pc[i * GR + j] = v;
        }
        __syncthreads();
        if (it == 0) {
            mm512(Ac, Bm, s1, t);
            __syncthreads();
            mm512(s1, Bm, s2, t);
            __syncthreads();
            float* na = s2; s2 = s1; s1 = Ac; Ac = na;
        } else if (it < 4) {
            mm512_dual(Pc, Ac, Bm, s1, s2, t);
            __syncthreads();
            mm512(s2, Bm, Pc, t);
            __syncthreads();
            float* na = Pc; float* np = s1; s1 = Ac; Ac = na; Pc = np;
        } else {
            mm512(Pc, Bm, s1, t);
            __syncthreads();
        }
    }
    const float* Pf = s1;
    for (int q = t; q < DOUT * 16; q += 512) {
        int row = q >> 4, c4 = q & 15;
        *(float4*)&gP[row * 64 + c4 * 4] = *(const float4*)&Pf[row * GR + c4 * 4];
    }
}

// ---------------------------------------------------------------------------
// Bjorck stage 4: Wo = sc * P @ W.
// ---------------------------------------------------------------------------
__global__ __launch_bounds__(512) void k4_wo(const float* __restrict__ W,
                                             const float* __restrict__ gP,
                                             const float* __restrict__ gSc,
                                             float* __restrict__ Wo) {
    __shared__ __align__(16) float Ps[DOUT * GR];
    int t = threadIdx.x;
    for (int q = t; q < DOUT * 16; q += 512) {
        int row = q >> 4, c4 = q & 15;
        *(float4*)&Ps[row * GR + c4 * 4] = *(const float4*)&gP[row * 64 + c4 * 4];
    }
    __syncthreads();
    float sc = gSc[0];
    int i0 = (t >> 4) * 2;
    int k0 = (t & 15) * 8;
    float4 acc0[2] = {}, acc1[2] = {};
    for (int j = 0; j < 64; ++j) {
        float4 w0 = *(const float4*)&W[j * DIN + k0];
        float4 w1 = *(const float4*)&W[j * DIN + k0 + 4];
#pragma unroll
        for (int r = 0; r < 2; ++r) {
            float pv = Ps[(i0 + r) * GR + j];
            acc0[r].x += pv * w0.x; acc0[r].y += pv * w0.y;
            acc0[r].z += pv * w0.z; acc0[r].w += pv * w0.w;
            acc1[r].x += pv * w1.x; acc1[r].y += pv * w1.y;
            acc1[r].z += pv * w1.z; acc1[r].w += pv * w1.w;
        }
    }
#pragma unroll
    for (int r = 0; r < 2; ++r) {
        float4 o0 = make_float4(sc * acc0[r].x, sc * acc0[r].y, sc * acc0[r].z, sc * acc0[r].w);
        float4 o1 = make_float4(sc * acc1[r].x, sc * acc1[r].y, sc * acc1[r].z, sc * acc1[r].w);
        *(float4*)&Wo[(i0 + r) * DIN + k0] = o0;
        *(float4*)&Wo[(i0 + r) * DIN + k0 + 4] = o1;
    }
}

// ---------------------------------------------------------------------------
// per-node prep
// ---------------------------------------------------------------------------
__global__ void node_prep(const float* __restrict__ diags,
                          const float* m1, const float* m2, const float* m3,
                          const float* e1, const float* e2, const float* e3,
                          float* __restrict__ d_e2m, float* __restrict__ d_e3p,
                          float* __restrict__ gso2, int n) {
    int i = blockIdx.x * blockDim.x + threadIdx.x;
    if (i >= n) return;
    float d = diags[i];
    float p1 = safe_pow(d, e1[0]);
    float p2 = safe_pow(d, e2[0]);
    float p3 = safe_pow(d, e3[0]);
    float vm2 = m2[0];
    d_e2m[i] = vm2 * p2;
    d_e3p[i] = p3;
    gso2[i] = m1[0] * p1 + vm2 * p2 * p3 + m3[0];
}

// ---------------------------------------------------------------------------
// xw = x @ Wo^T — register-tiled GEMM (64-node tile, 4x4 per thread)
// ---------------------------------------------------------------------------
#define XN 64
#define XS 132
__global__ __launch_bounds__(256) void xw_kernel(const float* __restrict__ x,
                                                 const float* __restrict__ Wo,
                                                 float* __restrict__ xw, int n) {
    __shared__ __align__(16) float xs[XN * XS];
    __shared__ __align__(16) float ws[DOUT * XS];
    int t = threadIdx.x;
    int base = blockIdx.x * XN;
    for (int f = t; f < DOUT * (DIN / 4); f += 256) {
        int r = f >> 5, c = f & 31;
        *(float4*)&ws[r * XS + c * 4] = *(const float4*)&Wo[r * DIN + c * 4];
    }
    for (int f = t; f < XN * (DIN / 4); f += 256) {
        int r = f >> 5, c = f & 31;
        int node = base + r;
        float4 v = make_float4(0.f, 0.f, 0.f, 0.f);
        if (node < n) v = *(const float4*)&x[(size_t)node * DIN + c * 4];
        *(float4*)&xs[r * XS + c * 4] = v;
    }
    __syncthreads();
    int tn = t >> 4;
    int td = t & 15;
    float acc[4][4] = {};
#pragma unroll 2
    for (int k4 = 0; k4 < DIN / 4; ++k4) {
        float4 a[4], w[4];
#pragma unroll
        for (int r = 0; r < 4; ++r) a[r] = *(const float4*)&xs[(tn * 4 + r) * XS + k4 * 4];
#pragma unroll
        for (int c = 0; c < 4; ++c) w[c] = *(const float4*)&ws[(td + c * 16) * XS + k4 * 4];
#pragma unroll
        for (int r = 0; r < 4; ++r)
#pragma unroll
            for (int c = 0; c < 4; ++c) acc[r][c] += dot4(a[r], w[c]);
    }
#pragma unroll
    for (int r = 0; r < 4; ++r) {
        int node = base + tn * 4 + r;
        if (node >= n) break;
#pragma unroll
        for (int c = 0; c < 4; ++c)
            xw[(size_t)node * DOUT + td + c * 16] = acc[r][c];
    }
}

// ---------------------------------------------------------------------------
// Sort pass B1: per-block bucket histograms (bucket = col >> 7).
// blk_hist[block * NBK_STRIDE + bucket] = count.
// ---------------------------------------------------------------------------
__global__ __launch_bounds__(256) void b1_hist(const int* __restrict__ ei,
                                               unsigned* __restrict__ blk_hist,
                                               int e_cnt, int chunk, int nbk) {
    __shared__ int h[NBK_STRIDE];
    int b = blockIdx.x, t = threadIdx.x;
    for (int j = t; j < NBK_STRIDE; j += 256) h[j] = 0;
    __syncthreads();
    int lo = b * chunk, hi = min(lo + chunk, e_cnt);
    for (int e = lo + t; e < hi; e += 256)
        atomicAdd(&h[ei[e_cnt + e] >> BK_SHIFT], 1);
    __syncthreads();
    for (int j = t; j < nbk; j += 256)
        blk_hist[(size_t)b * NBK_STRIDE + j] = (unsigned)h[j];
}

// ---------------------------------------------------------------------------
// Sort pass S: scan bucket totals -> bucket_offsets; convert blk_hist to
// per-(block,bucket) global base cursors. Single 1024-thread block.
// ---------------------------------------------------------------------------
__global__ __launch_bounds__(1024) void s_scan(unsigned* __restrict__ blk_hist,
                                               unsigned* __restrict__ bucket_offsets,
                                               int nbk, int e_cnt) {
    __shared__ int tot[1024];
    int t = threadIdx.x;
    int total = 0;
    if (t < nbk) {
        int run = 0;
        for (int b = 0; b < NBLK; ++b) {
            size_t idx = (size_t)b * NBK_STRIDE + t;
            int v = (int)blk_hist[idx];
            blk_hist[idx] = (unsigned)run;      // local prefix (base added below)
            run += v;
        }
        total = run;
    }
    tot[t] = total;
    __syncthreads();
    for (int d = 1; d < 1024; d <<= 1) {
        int u = (t >= d) ? tot[t - d] : 0;
        __syncthreads();
        tot[t] += u;
        __syncthreads();
    }
    int excl = tot[t] - total;
    if (t < nbk) {
        bucket_offsets[t] = (unsigned)excl;
        for (int b = 0; b < NBLK; ++b)
            blk_hist[(size_t)b * NBK_STRIDE + t] += (unsigned)excl;
    }
    if (t == 0) bucket_offsets[nbk] = (unsigned)e_cnt;
}

// ---------------------------------------------------------------------------
// Sort pass B2: scatter packed (src<<7 | lcol) into reserved per-block runs.
// Writes are dense + temporally local per block -> L2 merges to full lines.
// ---------------------------------------------------------------------------
__global__ __launch_bounds__(256) void b2_scatter(const int* __restrict__ ei,
                                                  const unsigned* __restrict__ blk_hist,
                                                  unsigned* __restrict__ bucketed,
                                                  int e_cnt, int chunk, int nbk) {
    __shared__ int cur[NBK_STRIDE];
    int b = blockIdx.x, t = threadIdx.x;
    for (int j = t; j < nbk; j += 256)
        cur[j] = (int)blk_hist[(size_t)b * NBK_STRIDE + j];
    __syncthreads();
    int lo = b * chunk, hi = min(lo + chunk, e_cnt);
    for (int e = lo + t; e < hi; e += 256) {
        int col = ei[e_cnt + e];
        int src = ei[e];
        int bkt = col >> BK_SHIFT;
        int pos = atomicAdd(&cur[bkt], 1);
        bucketed[pos] = ((unsigned)src << BK_SHIFT) | (unsigned)(col & (BK_COLS - 1));
    }
}

// ---------------------------------------------------------------------------
// Sort pass C: one block per bucket -> exact CSR (offsets + col-grouped srcs).
// ---------------------------------------------------------------------------
__global__ __launch_bounds__(256) void c_csr(const unsigned* __restrict__ bucketed,
                                             const unsigned* __restrict__ bucket_offsets,
                                             int* __restrict__ offsets,
                                             unsigned* __restrict__ srcs,
                                             int n, int e_cnt) {
    __shared__ unsigned sE[CCAP];
    __shared__ int sh[BK_COLS];
    __shared__ int sc[BK_COLS];
    __shared__ int pos_[BK_COLS];
    int b = blockIdx.x, t = threadIdx.x;
    int base = (int)bucket_offsets[b];
    int cnt = (int)bucket_offsets[b + 1] - base;
    bool fits = (cnt <= CCAP);
    if (fits)
        for (int i = t; i < cnt; i += 256) sE[i] = bucketed[base + i];
    if (t < BK_COLS) sh[t] = 0;
    __syncthreads();
    for (int i = t; i < cnt; i += 256) {
        unsigned p = fits ? sE[i] : bucketed[base + i];
        atomicAdd(&sh[p & (BK_COLS - 1)], 1);
    }
    __syncthreads();
    if (t < BK_COLS) sc[t] = sh[t];
    __syncthreads();
    for (int d = 1; d < BK_COLS; d <<= 1) {
        int u = 0;
        if (t < BK_COLS && t >= d) u = sc[t - d];
        __syncthreads();
        if (t < BK_COLS) sc[t] += u;
        __syncthreads();
    }
    if (t < BK_COLS) {
        int pre = sc[t] - sh[t];          // exclusive prefix
        int gc = b * BK_COLS + t;
        if (gc < n) offsets[gc] = base + pre;
        pos_[t] = pre;
    }
    if (b == 0 && t == 0) offsets[n] = e_cnt;
    __syncthreads();
    for (int i = t; i < cnt; i += 256) {
        unsigned p = fits ? sE[i] : bucketed[base + i];
        int lc = (int)(p & (BK_COLS - 1));
        int q = atomicAdd(&pos_[lc], 1);
        srcs[base + q] = p >> BK_SHIFT;
    }
}

// ---------------------------------------------------------------------------
// fused gather + self-loop + bias + log-softmax; one wave per node.
// weight recomputed: w_e = d_e2m[src] * d_e3p[node] (d_e3p hoisted per node).
// ---------------------------------------------------------------------------
__global__ __launch_bounds__(256) void gather_kernel(const int* __restrict__ offsets,
                                                     const unsigned* __restrict__ srcs,
                                                     const float* __restrict__ d_e2m,
                                                     const float* __restrict__ d_e3p,
                                                     const float* __restrict__ xw,
                                                     const float* __restrict__ gso2,
                                                     const float* __restrict__ b,
                                                     float* __restrict__ out, int n) {
    int lane = threadIdx.x & 63;
    int node = blockIdx.x * 4 + (threadIdx.x >> 6);
    if (node >= n) return;
    int lo = offsets[node], hi = offsets[node + 1];
    float v = gso2[node] * xw[(size_t)node * DOUT + lane] + 2.0f * b[lane];
    float dn = d_e3p[node];
    float acc = 0.f;
    int i = lo;
    for (; i + 4 <= hi; i += 4) {
        unsigned s0 = srcs[i], s1 = srcs[i + 1], s2 = srcs[i + 2], s3 = srcs[i + 3];
        float w0 = d_e2m[s0], w1 = d_e2m[s1], w2 = d_e2m[s2], w3 = d_e2m[s3];
        float a0 = xw[(size_t)s0 * DOUT + lane];
        float a1 = xw[(size_t)s1 * DOUT + lane];
        float a2 = xw[(size_t)s2 * DOUT + lane];
        float a3 = xw[(size_t)s3 * DOUT + lane];
        acc += w0 * a0 + w1 * a1 + w2 * a2 + w3 * a3;
    }
    for (; i < hi; ++i) {
        unsigned s = srcs[i];
        acc += d_e2m[s] * xw[(size_t)s * DOUT + lane];
    }
    v += dn * acc;
    float m = v;
#pragma unroll
    for (int d = 1; d < 64; d <<= 1) m = fmaxf(m, __shfl_xor(m, d));
    float s = expf(v - m);
#pragma unroll
    for (int d = 1; d < 64; d <<= 1) s += __shfl_xor(s, d);
    out[(size_t)node * DOUT + lane] = v - m - logf(s);
}

// ---------------------------------------------------------------------------
extern "C" void kernel_launch(void* const* d_in, const int* in_sizes, int n_in,
                              void* d_out, int out_size, void* d_ws, size_t ws_size,
                              hipStream_t stream) {
    const float* x     = (const float*)d_in[0];
    const int*   ei    = (const int*)d_in[1];
    const float* diags = (const float*)d_in[3];
    const float* W     = (const float*)d_in[4];
    const float* b     = (const float*)d_in[5];
    const float* m1    = (const float*)d_in[6];
    const float* m2    = (const float*)d_in[7];
    const float* m3    = (const float*)d_in[8];
    const float* e1    = (const float*)d_in[9];
    const float* e2    = (const float*)d_in[10];
    const float* e3    = (const float*)d_in[11];
    float* out = (float*)d_out;

    const int n = in_sizes[3];            // 100000
    const int e_cnt = in_sizes[1] / 2;    // 1600000
    const int nbk = (n + BK_COLS - 1) >> BK_SHIFT;          // 782 buckets
    const int chunk = (e_cnt + NBLK - 1) / NBLK;            // 25000 edges/block

    char* ws = (char*)d_ws;
    float*    Wo        = (float*)ws;                        // 8192 f (32KB)
    float*    d_e2m     = (float*)(ws + 32768);              // n
    float*    d_e3p     = d_e2m + n;                         // n
    float*    gso2      = d_e3p + n;                         // n
    float*    xw        = gso2 + n;                          // n*64
    int*      offsets   = (int*)(xw + (size_t)n * DOUT);     // n+4
    unsigned* srcs      = (unsigned*)(offsets + n + 4);      // e_cnt
    unsigned* bucketed  = srcs + e_cnt;                      // e_cnt
    unsigned* blk_hist  = bucketed + e_cnt;                  // NBLK*1024
    unsigned* boff      = blk_hist + (size_t)NBLK * NBK_STRIDE; // nbk+1
    uintptr_t gp = ((uintptr_t)(boff + nbk + 8) + 15) & ~(uintptr_t)15;
    float*    gG        = (float*)gp;                        // 4096
    float*    gH2       = gG + 4096;                         // 4096
    float*    gP        = gH2 + 4096;                        // 4096
    float*    gSc       = gP + 4096;                         // 2

    // Bjorck chain (small, single-block stages)
    k1_gram<<<1, 512, 0, stream>>>(W, gG, gH2);
    k2_power<<<1, 64, 0, stream>>>(gH2, gSc);
    k3_iter<<<1, 512, 0, stream>>>(gG, gSc, gP);
    k4_wo<<<1, 512, 0, stream>>>(W, gP, gSc, Wo);
    // node prep + feature transform
    node_prep<<<(n + 255) / 256, 256, 0, stream>>>(diags, m1, m2, m3, e1, e2, e3,
                                                   d_e2m, d_e3p, gso2, n);
    xw_kernel<<<(n + XN - 1) / XN, 256, 0, stream>>>(x, Wo, xw, n);
    // two-level bucket sort -> CSR
    b1_hist<<<NBLK, 256, 0, stream>>>(ei, blk_hist, e_cnt, chunk, nbk);
    s_scan<<<1, 1024, 0, stream>>>(blk_hist, boff, nbk, e_cnt);
    b2_scatter<<<NBLK, 256, 0, stream>>>(ei, blk_hist, bucketed, e_cnt, chunk, nbk);
    c_csr<<<nbk, 256, 0, stream>>>(bucketed, boff, offsets, srcs, n, e_cnt);
    // fused gather + softmax
    gather_kernel<<<(n + 3) / 4, 256, 0, stream>>>(offsets, srcs, d_e2m, d_e3p,
                                                   xw, gso2, b, out, n);
}

// Round 10
// 271.318 us; speedup vs baseline: 1.5317x; 1.0663x over previous
//
#include <hip/hip_runtime.h>
#include <math.h>

#define DIN 128
#define DOUT 64

#define NBLK 64             // binning blocks
#define BK_SHIFT 7          // 128 cols per bucket
#define BK_COLS 128
#define NBK_STRIDE 1024     // blk_hist row stride (buckets padded)
#define CCAP 4096           // max edges per bucket staged in LDS (mean ~2046)

__device__ __forceinline__ float safe_pow(float d, float e) {
    float p = powf(d, e);
    return isinf(p) ? 0.0f : p;
}

__device__ __forceinline__ float dot4(float4 a, float4 b) {
    return a.x * b.x + a.y * b.y + a.z * b.z + a.w * b.w;
}

// ---------------------------------------------------------------------------
// Plain multi-block 64x64 matmul: C = A @ B, Bsrc SYMMETRIC (rows read as
// cols). grid 8 (single) or 16 (dual: blocks 8..15 compute C2 = A2 @ B).
// Optional CB output (single passes only): CB = 1.5I - 0.5*C  (next B matrix)
// — a pure extra store, no operand transforms anywhere.
// ---------------------------------------------------------------------------
__global__ __launch_bounds__(256) void mm_pass(const float* A1, const float* A2,
                                               const float* Bsrc,
                                               float* C1, float* C2, float* CB) {
    int t = threadIdx.x;
    bool second = (blockIdx.x >= 8);
    int blk = blockIdx.x & 7;
    const float* As = second ? A2 : A1;
    float* Cs = second ? C2 : C1;
    int c = t & 63;
    int r0 = blk * 8 + (t >> 6) * 2;
    float acc0 = 0.f, acc1 = 0.f;
#pragma unroll
    for (int k4 = 0; k4 < 16; ++k4) {
        float4 b  = *(const float4*)&Bsrc[c * 64 + k4 * 4];
        float4 a0 = *(const float4*)&As[r0 * 64 + k4 * 4];
        float4 a1 = *(const float4*)&As[(r0 + 1) * 64 + k4 * 4];
        acc0 += dot4(a0, b);
        acc1 += dot4(a1, b);
    }
    Cs[r0 * 64 + c] = acc0;
    Cs[(r0 + 1) * 64 + c] = acc1;
    if (CB != nullptr && !second) {
        CB[r0 * 64 + c]       = ((r0 == c)     ? 1.5f : 0.0f) - 0.5f * acc0;
        CB[(r0 + 1) * 64 + c] = ((r0 + 1 == c) ? 1.5f : 0.0f) - 0.5f * acc1;
    }
}

// ---------------------------------------------------------------------------
// G = W @ W^T (64x64, K=128), 8 blocks.
// ---------------------------------------------------------------------------
__global__ __launch_bounds__(256) void gram_pass(const float* W, float* G) {
    int t = threadIdx.x;
    int c = t & 63;
    int r0 = blockIdx.x * 8 + (t >> 6) * 2;
    float acc0 = 0.f, acc1 = 0.f;
#pragma unroll
    for (int k4 = 0; k4 < 32; ++k4) {
        float4 b  = *(const float4*)&W[c * 128 + k4 * 4];
        float4 a0 = *(const float4*)&W[r0 * 128 + k4 * 4];
        float4 a1 = *(const float4*)&W[(r0 + 1) * 128 + k4 * 4];
        acc0 += dot4(a0, b);
        acc1 += dot4(a1, b);
    }
    G[r0 * 64 + c] = acc0;
    G[(r0 + 1) * 64 + c] = acc1;
}

// ---------------------------------------------------------------------------
// power iteration on H2 = G^4 (trace-scaled, 8 raw iters + Rayleigh), 1 wave.
// gSc[0] = 1/(1.1 sigma), gSc[1] = 1/(1.21 sigma^2).  (identical to round 8)
// ---------------------------------------------------------------------------
__global__ __launch_bounds__(64) void power_pass(const float* gH2, float* gSc) {
    int t = threadIdx.x;
    float tr = gH2[t * 65];
#pragma unroll
    for (int d = 1; d < 64; d <<= 1) tr += __shfl_xor(tr, d);
    float inv_tr = 1.0f / tr;
    float4 g4[16];
#pragma unroll
    for (int j4 = 0; j4 < 16; ++j4) {
        float4 v = *(const float4*)&gH2[t * 64 + j4 * 4];
        v.x *= inv_tr; v.y *= inv_tr; v.z *= inv_tr; v.w *= inv_tr;
        g4[j4] = v;
    }
    unsigned h = (unsigned)t * 2654435761u;
    float xv = 0.5f + (float)((h >> 17) & 0x7fff) * (1.0f / 32768.0f);
    float yv = 0.f;
    for (int it = 0; it < 8; ++it) {
        float p0 = 0.f, p1 = 0.f, p2 = 0.f, p3 = 0.f;
#pragma unroll
        for (int j4 = 0; j4 < 16; ++j4) {
            float4 xx;
            xx.x = __shfl(xv, j4 * 4 + 0);
            xx.y = __shfl(xv, j4 * 4 + 1);
            xx.z = __shfl(xv, j4 * 4 + 2);
            xx.w = __shfl(xv, j4 * 4 + 3);
            float dd = dot4(g4[j4], xx);
            if (j4 < 4) p0 += dd; else if (j4 < 8) p1 += dd;
            else if (j4 < 12) p2 += dd; else p3 += dd;
        }
        yv = (p0 + p1) + (p2 + p3);
        if (it < 7) xv = yv;
    }
    float num = xv * yv, den = xv * xv;
#pragma unroll
    for (int d = 1; d < 64; d <<= 1) {
        num += __shfl_xor(num, d);
        den += __shfl_xor(den, d);
    }
    if (t == 0) {
        float lam_h2 = tr * num / den;        // = sigma^8
        float sig = powf(lam_h2, 0.125f);
        gSc[0] = 1.0f / (1.1f * sig);
        gSc[1] = 1.0f / (1.21f * sig * sig);
    }
}

// ---------------------------------------------------------------------------
// prep: A0 = rs*G;  B0 = 1.5I - 0.5*A0   (elementwise, 4096 elems)
// ---------------------------------------------------------------------------
__global__ __launch_bounds__(256) void prep_pass(const float* gG, const float* gSc,
                                                 float* gA0, float* gB0) {
    int idx = blockIdx.x * 256 + threadIdx.x;
    if (idx >= 4096) return;
    float rs = gSc[1];
    int r = idx >> 6, c = idx & 63;
    float a0 = rs * gG[idx];
    gA0[idx] = a0;
    gB0[idx] = ((r == c) ? 1.5f : 0.0f) - 0.5f * a0;
}

// ---------------------------------------------------------------------------
// Wo = sc * P @ W  (64x128), 8 blocks; W column reads coalesced across lanes.
// ---------------------------------------------------------------------------
__global__ __launch_bounds__(256) void wo_pass(const float* W, const float* P,
                                               const float* gSc, float* Wo) {
    int t = threadIdx.x;
    int c = t & 63;
    int r0 = blockIdx.x * 8 + (t >> 6) * 2;
    float a00 = 0.f, a01 = 0.f, a10 = 0.f, a11 = 0.f;
#pragma unroll 4
    for (int j = 0; j < 64; ++j) {
        float p0 = P[r0 * 64 + j];
        float p1 = P[(r0 + 1) * 64 + j];
        float w0 = W[j * 128 + c];
        float w1 = W[j * 128 + c + 64];
        a00 += p0 * w0; a01 += p0 * w1;
        a10 += p1 * w0; a11 += p1 * w1;
    }
    float sc = gSc[0];
    Wo[r0 * 128 + c]            = sc * a00;
    Wo[r0 * 128 + c + 64]       = sc * a01;
    Wo[(r0 + 1) * 128 + c]      = sc * a10;
    Wo[(r0 + 1) * 128 + c + 64] = sc * a11;
}

// ---------------------------------------------------------------------------
// per-node prep
// ---------------------------------------------------------------------------
__global__ void node_prep(const float* __restrict__ diags,
                          const float* m1, const float* m2, const float* m3,
                          const float* e1, const float* e2, const float* e3,
                          float* __restrict__ d_e2m, float* __restrict__ d_e3p,
                          float* __restrict__ gso2, int n) {
    int i = blockIdx.x * blockDim.x + threadIdx.x;
    if (i >= n) return;
    float d = diags[i];
    float p1 = safe_pow(d, e1[0]);
    float p2 = safe_pow(d, e2[0]);
    float p3 = safe_pow(d, e3[0]);
    float vm2 = m2[0];
    d_e2m[i] = vm2 * p2;
    d_e3p[i] = p3;
    gso2[i] = m1[0] * p1 + vm2 * p2 * p3 + m3[0];
}

// ---------------------------------------------------------------------------
// xw = x @ Wo^T — register-tiled GEMM (64-node tile, 4x4 per thread)
// ---------------------------------------------------------------------------
#define XN 64
#define XS 132
__global__ __launch_bounds__(256) void xw_kernel(const float* __restrict__ x,
                                                 const float* __restrict__ Wo,
                                                 float* __restrict__ xw, int n) {
    __shared__ __align__(16) float xs[XN * XS];
    __shared__ __align__(16) float ws[DOUT * XS];
    int t = threadIdx.x;
    int base = blockIdx.x * XN;
    for (int f = t; f < DOUT * (DIN / 4); f += 256) {
        int r = f >> 5, c = f & 31;
        *(float4*)&ws[r * XS + c * 4] = *(const float4*)&Wo[r * DIN + c * 4];
    }
    for (int f = t; f < XN * (DIN / 4); f += 256) {
        int r = f >> 5, c = f & 31;
        int node = base + r;
        float4 v = make_float4(0.f, 0.f, 0.f, 0.f);
        if (node < n) v = *(const float4*)&x[(size_t)node * DIN + c * 4];
        *(float4*)&xs[r * XS + c * 4] = v;
    }
    __syncthreads();
    int tn = t >> 4;
    int td = t & 15;
    float acc[4][4] = {};
#pragma unroll 2
    for (int k4 = 0; k4 < DIN / 4; ++k4) {
        float4 a[4], w[4];
#pragma unroll
        for (int r = 0; r < 4; ++r) a[r] = *(const float4*)&xs[(tn * 4 + r) * XS + k4 * 4];
#pragma unroll
        for (int c = 0; c < 4; ++c) w[c] = *(const float4*)&ws[(td + c * 16) * XS + k4 * 4];
#pragma unroll
        for (int r = 0; r < 4; ++r)
#pragma unroll
            for (int c = 0; c < 4; ++c) acc[r][c] += dot4(a[r], w[c]);
    }
#pragma unroll
    for (int r = 0; r < 4; ++r) {
        int node = base + tn * 4 + r;
        if (node >= n) break;
#pragma unroll
        for (int c = 0; c < 4; ++c)
            xw[(size_t)node * DOUT + td + c * 16] = acc[r][c];
    }
}

// ---------------------------------------------------------------------------
// Sort pass B1: per-block bucket histograms (bucket = col >> 7).
// ---------------------------------------------------------------------------
__global__ __launch_bounds__(256) void b1_hist(const int* __restrict__ ei,
                                               unsigned* __restrict__ blk_hist,
                                               int e_cnt, int chunk, int nbk) {
    __shared__ int h[NBK_STRIDE];
    int b = blockIdx.x, t = threadIdx.x;
    for (int j = t; j < NBK_STRIDE; j += 256) h[j] = 0;
    __syncthreads();
    int lo = b * chunk, hi = min(lo + chunk, e_cnt);
    for (int e = lo + t; e < hi; e += 256)
        atomicAdd(&h[ei[e_cnt + e] >> BK_SHIFT], 1);
    __syncthreads();
    for (int j = t; j < nbk; j += 256)
        blk_hist[(size_t)b * NBK_STRIDE + j] = (unsigned)h[j];
}

// ---------------------------------------------------------------------------
// Sort pass S: scan bucket totals -> bucket_offsets + per-(block,bucket) bases.
// ---------------------------------------------------------------------------
__global__ __launch_bounds__(1024) void s_scan(unsigned* __restrict__ blk_hist,
                                               unsigned* __restrict__ bucket_offsets,
                                               int nbk, int e_cnt) {
    __shared__ int tot[1024];
    int t = threadIdx.x;
    int total = 0;
    if (t < nbk) {
        int run = 0;
        for (int b = 0; b < NBLK; ++b) {
            size_t idx = (size_t)b * NBK_STRIDE + t;
            int v = (int)blk_hist[idx];
            blk_hist[idx] = (unsigned)run;
            run += v;
        }
        total = run;
    }
    tot[t] = total;
    __syncthreads();
    for (int d = 1; d < 1024; d <<= 1) {
        int u = (t >= d) ? tot[t - d] : 0;
        __syncthreads();
        tot[t] += u;
        __syncthreads();
    }
    int excl = tot[t] - total;
    if (t < nbk) {
        bucket_offsets[t] = (unsigned)excl;
        for (int b = 0; b < NBLK; ++b)
            blk_hist[(size_t)b * NBK_STRIDE + t] += (unsigned)excl;
    }
    if (t == 0) bucket_offsets[nbk] = (unsigned)e_cnt;
}

// ---------------------------------------------------------------------------
// Sort pass B2: scatter packed (src<<7 | lcol) into reserved per-block runs.
// ---------------------------------------------------------------------------
__global__ __launch_bounds__(256) void b2_scatter(const int* __restrict__ ei,
                                                  const unsigned* __restrict__ blk_hist,
                                                  unsigned* __restrict__ bucketed,
                                                  int e_cnt, int chunk, int nbk) {
    __shared__ int cur[NBK_STRIDE];
    int b = blockIdx.x, t = threadIdx.x;
    for (int j = t; j < nbk; j += 256)
        cur[j] = (int)blk_hist[(size_t)b * NBK_STRIDE + j];
    __syncthreads();
    int lo = b * chunk, hi = min(lo + chunk, e_cnt);
    for (int e = lo + t; e < hi; e += 256) {
        int col = ei[e_cnt + e];
        int src = ei[e];
        int bkt = col >> BK_SHIFT;
        int pos = atomicAdd(&cur[bkt], 1);
        bucketed[pos] = ((unsigned)src << BK_SHIFT) | (unsigned)(col & (BK_COLS - 1));
    }
}

// ---------------------------------------------------------------------------
// Sort pass C: one block per bucket -> exact CSR.
// ---------------------------------------------------------------------------
__global__ __launch_bounds__(256) void c_csr(const unsigned* __restrict__ bucketed,
                                             const unsigned* __restrict__ bucket_offsets,
                                             int* __restrict__ offsets,
                                             unsigned* __restrict__ srcs,
                                             int n, int e_cnt) {
    __shared__ unsigned sE[CCAP];
    __shared__ int sh[BK_COLS];
    __shared__ int sc[BK_COLS];
    __shared__ int pos_[BK_COLS];
    int b = blockIdx.x, t = threadIdx.x;
    int base = (int)bucket_offsets[b];
    int cnt = (int)bucket_offsets[b + 1] - base;
    bool fits = (cnt <= CCAP);
    if (fits)
        for (int i = t; i < cnt; i += 256) sE[i] = bucketed[base + i];
    if (t < BK_COLS) sh[t] = 0;
    __syncthreads();
    for (int i = t; i < cnt; i += 256) {
        unsigned p = fits ? sE[i] : bucketed[base + i];
        atomicAdd(&sh[p & (BK_COLS - 1)], 1);
    }
    __syncthreads();
    if (t < BK_COLS) sc[t] = sh[t];
    __syncthreads();
    for (int d = 1; d < BK_COLS; d <<= 1) {
        int u = 0;
        if (t < BK_COLS && t >= d) u = sc[t - d];
        __syncthreads();
        if (t < BK_COLS) sc[t] += u;
        __syncthreads();
    }
    if (t < BK_COLS) {
        int pre = sc[t] - sh[t];
        int gc = b * BK_COLS + t;
        if (gc < n) offsets[gc] = base + pre;
        pos_[t] = pre;
    }
    if (b == 0 && t == 0) offsets[n] = e_cnt;
    __syncthreads();
    for (int i = t; i < cnt; i += 256) {
        unsigned p = fits ? sE[i] : bucketed[base + i];
        int lc = (int)(p & (BK_COLS - 1));
        int q = atomicAdd(&pos_[lc], 1);
        srcs[base + q] = p >> BK_SHIFT;
    }
}

// ---------------------------------------------------------------------------
// fused gather + self-loop + bias + log-softmax; one wave per node.
// ---------------------------------------------------------------------------
__global__ __launch_bounds__(256) void gather_kernel(const int* __restrict__ offsets,
                                                     const unsigned* __restrict__ srcs,
                                                     const float* __restrict__ d_e2m,
                                                     const float* __restrict__ d_e3p,
                                                     const float* __restrict__ xw,
                                                     const float* __restrict__ gso2,
                                                     const float* __restrict__ b,
                                                     float* __restrict__ out, int n) {
    int lane = threadIdx.x & 63;
    int node = blockIdx.x * 4 + (threadIdx.x >> 6);
    if (node >= n) return;
    int lo = offsets[node], hi = offsets[node + 1];
    float v = gso2[node] * xw[(size_t)node * DOUT + lane] + 2.0f * b[lane];
    float dn = d_e3p[node];
    float acc = 0.f;
    int i = lo;
    for (; i + 4 <= hi; i += 4) {
        unsigned s0 = srcs[i], s1 = srcs[i + 1], s2 = srcs[i + 2], s3 = srcs[i + 3];
        float w0 = d_e2m[s0], w1 = d_e2m[s1], w2 = d_e2m[s2], w3 = d_e2m[s3];
        float a0 = xw[(size_t)s0 * DOUT + lane];
        float a1 = xw[(size_t)s1 * DOUT + lane];
        float a2 = xw[(size_t)s2 * DOUT + lane];
        float a3 = xw[(size_t)s3 * DOUT + lane];
        acc += w0 * a0 + w1 * a1 + w2 * a2 + w3 * a3;
    }
    for (; i < hi; ++i) {
        unsigned s = srcs[i];
        acc += d_e2m[s] * xw[(size_t)s * DOUT + lane];
    }
    v += dn * acc;
    float m = v;
#pragma unroll
    for (int d = 1; d < 64; d <<= 1) m = fmaxf(m, __shfl_xor(m, d));
    float s = expf(v - m);
#pragma unroll
    for (int d = 1; d < 64; d <<= 1) s += __shfl_xor(s, d);
    out[(size_t)node * DOUT + lane] = v - m - logf(s);
}

// ---------------------------------------------------------------------------
extern "C" void kernel_launch(void* const* d_in, const int* in_sizes, int n_in,
                              void* d_out, int out_size, void* d_ws, size_t ws_size,
                              hipStream_t stream) {
    const float* x     = (const float*)d_in[0];
    const int*   ei    = (const int*)d_in[1];
    const float* diags = (const float*)d_in[3];
    const float* W     = (const float*)d_in[4];
    const float* b     = (const float*)d_in[5];
    const float* m1    = (const float*)d_in[6];
    const float* m2    = (const float*)d_in[7];
    const float* m3    = (const float*)d_in[8];
    const float* e1    = (const float*)d_in[9];
    const float* e2    = (const float*)d_in[10];
    const float* e3    = (const float*)d_in[11];
    float* out = (float*)d_out;

    const int n = in_sizes[3];            // 100000
    const int e_cnt = in_sizes[1] / 2;    // 1600000
    const int nbk = (n + BK_COLS - 1) >> BK_SHIFT;          // 782 buckets
    const int chunk = (e_cnt + NBLK - 1) / NBLK;            // 25000 edges/block

    char* ws = (char*)d_ws;
    // --- small-matrix region first (fixed offsets, first ~256KB) ---
    float*    Wo   = (float*)ws;                 // 8192 floats = 32KB
    float*    gG   = (float*)(ws + 32768);       // 12 x 4096 floats
    float*    gT   = gG  + 4096;
    float*    gA   = gT  + 4096;
    float*    gAn  = gA  + 4096;
    float*    gA0  = gAn + 4096;
    float*    gP   = gA0 + 4096;
    float*    gPn  = gP  + 4096;
    float*    gB0  = gPn + 4096;
    float*    gB1  = gB0 + 4096;
    float*    gB2  = gB1 + 4096;
    float*    gB3  = gB2 + 4096;
    float*    gB4  = gB3 + 4096;
    float*    gSc  = gB4 + 4096;                 // 2 floats (pad to 64)
    // --- big arrays ---
    float*    d_e2m    = gSc + 64;               // n
    float*    d_e3p    = d_e2m + n;              // n
    float*    gso2     = d_e3p + n;              // n
    float*    xw       = gso2 + n;               // n*64
    int*      offsets  = (int*)(xw + (size_t)n * DOUT);     // n+4
    unsigned* srcs     = (unsigned*)(offsets + n + 4);      // e_cnt
    unsigned* bucketed = srcs + e_cnt;                      // e_cnt
    unsigned* blk_hist = bucketed + e_cnt;                  // NBLK*1024
    unsigned* boff     = blk_hist + (size_t)NBLK * NBK_STRIDE; // nbk+1

    // ---- Bjorck chain: 15 small dispatches, all plain matmuls -------------
    gram_pass<<<8, 256, 0, stream>>>(W, gG);                              // G
    mm_pass<<<8, 256, 0, stream>>>(gG, nullptr, gG, gT, nullptr, nullptr); // H = G^2
    mm_pass<<<8, 256, 0, stream>>>(gT, nullptr, gT, gA, nullptr, nullptr); // H2 = G^4
    power_pass<<<1, 64, 0, stream>>>(gA, gSc);                            // sc, rs
    prep_pass<<<16, 256, 0, stream>>>(gG, gSc, gA0, gB0);                 // A0, B0
    mm_pass<<<8, 256, 0, stream>>>(gA0, nullptr, gB0, gT, nullptr, nullptr); // T = A0@B0
    mm_pass<<<8, 256, 0, stream>>>(gT, nullptr, gB0, gA, nullptr, gB1);   // A1 (+B1)
    mm_pass<<<16, 256, 0, stream>>>(gB0, gA, gB1, gP, gT, nullptr);       // P=B0B1, T=A1B1
    mm_pass<<<8, 256, 0, stream>>>(gT, nullptr, gB1, gAn, nullptr, gB2);  // A2 (+B2)
    mm_pass<<<16, 256, 0, stream>>>(gP, gAn, gB2, gPn, gT, nullptr);      // P=PB2, T=A2B2
    mm_pass<<<8, 256, 0, stream>>>(gT, nullptr, gB2, gA, nullptr, gB3);   // A3 (+B3)
    mm_pass<<<16, 256, 0, stream>>>(gPn, gA, gB3, gP, gT, nullptr);       // P=PB3, T=A3B3
    mm_pass<<<8, 256, 0, stream>>>(gT, nullptr, gB3, gAn, nullptr, gB4);  // A4 (+B4)
    mm_pass<<<8, 256, 0, stream>>>(gP, nullptr, gB4, gPn, nullptr, nullptr); // P final
    wo_pass<<<8, 256, 0, stream>>>(W, gPn, gSc, Wo);                      // Wo

    // ---- node prep + feature transform ------------------------------------
    node_prep<<<(n + 255) / 256, 256, 0, stream>>>(diags, m1, m2, m3, e1, e2, e3,
                                                   d_e2m, d_e3p, gso2, n);
    xw_kernel<<<(n + XN - 1) / XN, 256, 0, stream>>>(x, Wo, xw, n);
    // ---- two-level bucket sort -> CSR --------------------------------------
    b1_hist<<<NBLK, 256, 0, stream>>>(ei, blk_hist, e_cnt, chunk, nbk);
    s_scan<<<1, 1024, 0, stream>>>(blk_hist, boff, nbk, e_cnt);
    b2_scatter<<<NBLK, 256, 0, stream>>>(ei, blk_hist, bucketed, e_cnt, chunk, nbk);
    c_csr<<<nbk, 256, 0, stream>>>(bucketed, boff, offsets, srcs, n, e_cnt);
    // ---- fused gather + softmax --------------------------------------------
    gather_kernel<<<(n + 3) / 4, 256, 0, stream>>>(offsets, srcs, d_e2m, d_e3p,
                                                   xw, gso2, b, out, n);
}

// Round 11
// 265.075 us; speedup vs baseline: 1.5678x; 1.0236x over previous
//
#include <hip/hip_runtime.h>
#include <math.h>

#define DIN 128
#define DOUT 64

#define NBLK 64             // binning blocks
#define BK_SHIFT 7          // 128 cols per bucket
#define BK_COLS 128
#define NBK_STRIDE 1024     // blk_hist row stride (buckets padded)
#define CCAP 4096           // max edges per bucket staged in LDS (mean ~2046)

__device__ __forceinline__ float safe_pow(float d, float e) {
    float p = powf(d, e);
    return isinf(p) ? 0.0f : p;
}

__device__ __forceinline__ float dot4(float4 a, float4 b) {
    return a.x * b.x + a.y * b.y + a.z * b.z + a.w * b.w;
}

// fp32 -> bf16 (round-to-nearest-even), as raw ushort
__device__ __forceinline__ unsigned short f32_to_bf16(float f) {
    unsigned bits = __float_as_uint(f);
    unsigned r = (bits + 0x7FFFu + ((bits >> 16) & 1u)) >> 16;
    return (unsigned short)r;
}
// bf16 (raw ushort) -> fp32
__device__ __forceinline__ float bf16_to_f32(unsigned short u) {
    return __uint_as_float((unsigned)u << 16);
}

// ---------------------------------------------------------------------------
// Plain multi-block 64x64 matmul: C = A @ B, Bsrc SYMMETRIC (rows read as
// cols). grid 8 (single) or 16 (dual: blocks 8..15 compute C2 = A2 @ B).
// Optional CB output (single passes only): CB = 1.5I - 0.5*C.
// ---------------------------------------------------------------------------
__global__ __launch_bounds__(256) void mm_pass(const float* A1, const float* A2,
                                               const float* Bsrc,
                                               float* C1, float* C2, float* CB) {
    int t = threadIdx.x;
    bool second = (blockIdx.x >= 8);
    int blk = blockIdx.x & 7;
    const float* As = second ? A2 : A1;
    float* Cs = second ? C2 : C1;
    int c = t & 63;
    int r0 = blk * 8 + (t >> 6) * 2;
    float acc0 = 0.f, acc1 = 0.f;
#pragma unroll
    for (int k4 = 0; k4 < 16; ++k4) {
        float4 b  = *(const float4*)&Bsrc[c * 64 + k4 * 4];
        float4 a0 = *(const float4*)&As[r0 * 64 + k4 * 4];
        float4 a1 = *(const float4*)&As[(r0 + 1) * 64 + k4 * 4];
        acc0 += dot4(a0, b);
        acc1 += dot4(a1, b);
    }
    Cs[r0 * 64 + c] = acc0;
    Cs[(r0 + 1) * 64 + c] = acc1;
    if (CB != nullptr && !second) {
        CB[r0 * 64 + c]       = ((r0 == c)     ? 1.5f : 0.0f) - 0.5f * acc0;
        CB[(r0 + 1) * 64 + c] = ((r0 + 1 == c) ? 1.5f : 0.0f) - 0.5f * acc1;
    }
}

// ---------------------------------------------------------------------------
// G = W @ W^T (64x64, K=128), 8 blocks.
// ---------------------------------------------------------------------------
__global__ __launch_bounds__(256) void gram_pass(const float* W, float* G) {
    int t = threadIdx.x;
    int c = t & 63;
    int r0 = blockIdx.x * 8 + (t >> 6) * 2;
    float acc0 = 0.f, acc1 = 0.f;
#pragma unroll
    for (int k4 = 0; k4 < 32; ++k4) {
        float4 b  = *(const float4*)&W[c * 128 + k4 * 4];
        float4 a0 = *(const float4*)&W[r0 * 128 + k4 * 4];
        float4 a1 = *(const float4*)&W[(r0 + 1) * 128 + k4 * 4];
        acc0 += dot4(a0, b);
        acc1 += dot4(a1, b);
    }
    G[r0 * 64 + c] = acc0;
    G[(r0 + 1) * 64 + c] = acc1;
}

// ---------------------------------------------------------------------------
// power iteration on H2 = G^4 (trace-scaled, 8 raw iters + Rayleigh), 1 wave.
// ---------------------------------------------------------------------------
__global__ __launch_bounds__(64) void power_pass(const float* gH2, float* gSc) {
    int t = threadIdx.x;
    float tr = gH2[t * 65];
#pragma unroll
    for (int d = 1; d < 64; d <<= 1) tr += __shfl_xor(tr, d);
    float inv_tr = 1.0f / tr;
    float4 g4[16];
#pragma unroll
    for (int j4 = 0; j4 < 16; ++j4) {
        float4 v = *(const float4*)&gH2[t * 64 + j4 * 4];
        v.x *= inv_tr; v.y *= inv_tr; v.z *= inv_tr; v.w *= inv_tr;
        g4[j4] = v;
    }
    unsigned h = (unsigned)t * 2654435761u;
    float xv = 0.5f + (float)((h >> 17) & 0x7fff) * (1.0f / 32768.0f);
    float yv = 0.f;
    for (int it = 0; it < 8; ++it) {
        float p0 = 0.f, p1 = 0.f, p2 = 0.f, p3 = 0.f;
#pragma unroll
        for (int j4 = 0; j4 < 16; ++j4) {
            float4 xx;
            xx.x = __shfl(xv, j4 * 4 + 0);
            xx.y = __shfl(xv, j4 * 4 + 1);
            xx.z = __shfl(xv, j4 * 4 + 2);
            xx.w = __shfl(xv, j4 * 4 + 3);
            float dd = dot4(g4[j4], xx);
            if (j4 < 4) p0 += dd; else if (j4 < 8) p1 += dd;
            else if (j4 < 12) p2 += dd; else p3 += dd;
        }
        yv = (p0 + p1) + (p2 + p3);
        if (it < 7) xv = yv;
    }
    float num = xv * yv, den = xv * xv;
#pragma unroll
    for (int d = 1; d < 64; d <<= 1) {
        num += __shfl_xor(num, d);
        den += __shfl_xor(den, d);
    }
    if (t == 0) {
        float lam_h2 = tr * num / den;        // = sigma^8
        float sig = powf(lam_h2, 0.125f);
        gSc[0] = 1.0f / (1.1f * sig);
        gSc[1] = 1.0f / (1.21f * sig * sig);
    }
}

// ---------------------------------------------------------------------------
// prep: A0 = rs*G;  B0 = 1.5I - 0.5*A0
// ---------------------------------------------------------------------------
__global__ __launch_bounds__(256) void prep_pass(const float* gG, const float* gSc,
                                                 float* gA0, float* gB0) {
    int idx = blockIdx.x * 256 + threadIdx.x;
    if (idx >= 4096) return;
    float rs = gSc[1];
    int r = idx >> 6, c = idx & 63;
    float a0 = rs * gG[idx];
    gA0[idx] = a0;
    gB0[idx] = ((r == c) ? 1.5f : 0.0f) - 0.5f * a0;
}

// ---------------------------------------------------------------------------
// Wo = sc * P @ W  (64x128), 8 blocks.
// ---------------------------------------------------------------------------
__global__ __launch_bounds__(256) void wo_pass(const float* W, const float* P,
                                               const float* gSc, float* Wo) {
    int t = threadIdx.x;
    int c = t & 63;
    int r0 = blockIdx.x * 8 + (t >> 6) * 2;
    float a00 = 0.f, a01 = 0.f, a10 = 0.f, a11 = 0.f;
#pragma unroll 4
    for (int j = 0; j < 64; ++j) {
        float p0 = P[r0 * 64 + j];
        float p1 = P[(r0 + 1) * 64 + j];
        float w0 = W[j * 128 + c];
        float w1 = W[j * 128 + c + 64];
        a00 += p0 * w0; a01 += p0 * w1;
        a10 += p1 * w0; a11 += p1 * w1;
    }
    float sc = gSc[0];
    Wo[r0 * 128 + c]            = sc * a00;
    Wo[r0 * 128 + c + 64]       = sc * a01;
    Wo[(r0 + 1) * 128 + c]      = sc * a10;
    Wo[(r0 + 1) * 128 + c + 64] = sc * a11;
}

// ---------------------------------------------------------------------------
// per-node prep
// ---------------------------------------------------------------------------
__global__ void node_prep(const float* __restrict__ diags,
                          const float* m1, const float* m2, const float* m3,
                          const float* e1, const float* e2, const float* e3,
                          float* __restrict__ d_e2m, float* __restrict__ d_e3p,
                          float* __restrict__ gso2, int n) {
    int i = blockIdx.x * blockDim.x + threadIdx.x;
    if (i >= n) return;
    float d = diags[i];
    float p1 = safe_pow(d, e1[0]);
    float p2 = safe_pow(d, e2[0]);
    float p3 = safe_pow(d, e3[0]);
    float vm2 = m2[0];
    d_e2m[i] = vm2 * p2;
    d_e3p[i] = p3;
    gso2[i] = m1[0] * p1 + vm2 * p2 * p3 + m3[0];
}

// ---------------------------------------------------------------------------
// xw = x @ Wo^T — register-tiled GEMM; OUTPUT IN BF16 (halves gather traffic).
// Stores: per (r,c) instr, 16 consecutive td lanes write 2B each -> 32B runs.
// ---------------------------------------------------------------------------
#define XN 64
#define XS 132
__global__ __launch_bounds__(256) void xw_kernel(const float* __restrict__ x,
                                                 const float* __restrict__ Wo,
                                                 unsigned short* __restrict__ xwb,
                                                 int n) {
    __shared__ __align__(16) float xs[XN * XS];
    __shared__ __align__(16) float ws[DOUT * XS];
    int t = threadIdx.x;
    int base = blockIdx.x * XN;
    for (int f = t; f < DOUT * (DIN / 4); f += 256) {
        int r = f >> 5, c = f & 31;
        *(float4*)&ws[r * XS + c * 4] = *(const float4*)&Wo[r * DIN + c * 4];
    }
    for (int f = t; f < XN * (DIN / 4); f += 256) {
        int r = f >> 5, c = f & 31;
        int node = base + r;
        float4 v = make_float4(0.f, 0.f, 0.f, 0.f);
        if (node < n) v = *(const float4*)&x[(size_t)node * DIN + c * 4];
        *(float4*)&xs[r * XS + c * 4] = v;
    }
    __syncthreads();
    int tn = t >> 4;
    int td = t & 15;
    float acc[4][4] = {};
#pragma unroll 2
    for (int k4 = 0; k4 < DIN / 4; ++k4) {
        float4 a[4], w[4];
#pragma unroll
        for (int r = 0; r < 4; ++r) a[r] = *(const float4*)&xs[(tn * 4 + r) * XS + k4 * 4];
#pragma unroll
        for (int c = 0; c < 4; ++c) w[c] = *(const float4*)&ws[(td + c * 16) * XS + k4 * 4];
#pragma unroll
        for (int r = 0; r < 4; ++r)
#pragma unroll
            for (int c = 0; c < 4; ++c) acc[r][c] += dot4(a[r], w[c]);
    }
#pragma unroll
    for (int r = 0; r < 4; ++r) {
        int node = base + tn * 4 + r;
        if (node >= n) break;
#pragma unroll
        for (int c = 0; c < 4; ++c)
            xwb[(size_t)node * DOUT + td + c * 16] = f32_to_bf16(acc[r][c]);
    }
}

// ---------------------------------------------------------------------------
// Sort pass B1: per-block bucket histograms (bucket = col >> 7).
// ---------------------------------------------------------------------------
__global__ __launch_bounds__(256) void b1_hist(const int* __restrict__ ei,
                                               unsigned* __restrict__ blk_hist,
                                               int e_cnt, int chunk, int nbk) {
    __shared__ int h[NBK_STRIDE];
    int b = blockIdx.x, t = threadIdx.x;
    for (int j = t; j < NBK_STRIDE; j += 256) h[j] = 0;
    __syncthreads();
    int lo = b * chunk, hi = min(lo + chunk, e_cnt);
    for (int e = lo + t; e < hi; e += 256)
        atomicAdd(&h[ei[e_cnt + e] >> BK_SHIFT], 1);
    __syncthreads();
    for (int j = t; j < nbk; j += 256)
        blk_hist[(size_t)b * NBK_STRIDE + j] = (unsigned)h[j];
}

// ---------------------------------------------------------------------------
// Sort pass S: scan bucket totals -> bucket_offsets + per-(block,bucket) bases.
// ---------------------------------------------------------------------------
__global__ __launch_bounds__(1024) void s_scan(unsigned* __restrict__ blk_hist,
                                               unsigned* __restrict__ bucket_offsets,
                                               int nbk, int e_cnt) {
    __shared__ int tot[1024];
    int t = threadIdx.x;
    int total = 0;
    if (t < nbk) {
        int run = 0;
        for (int b = 0; b < NBLK; ++b) {
            size_t idx = (size_t)b * NBK_STRIDE + t;
            int v = (int)blk_hist[idx];
            blk_hist[idx] = (unsigned)run;
            run += v;
        }
        total = run;
    }
    tot[t] = total;
    __syncthreads();
    for (int d = 1; d < 1024; d <<= 1) {
        int u = (t >= d) ? tot[t - d] : 0;
        __syncthreads();
        tot[t] += u;
        __syncthreads();
    }
    int excl = tot[t] - total;
    if (t < nbk) {
        bucket_offsets[t] = (unsigned)excl;
        for (int b = 0; b < NBLK; ++b)
            blk_hist[(size_t)b * NBK_STRIDE + t] += (unsigned)excl;
    }
    if (t == 0) bucket_offsets[nbk] = (unsigned)e_cnt;
}

// ---------------------------------------------------------------------------
// Sort pass B2: scatter packed (src<<7 | lcol) into reserved per-block runs.
// ---------------------------------------------------------------------------
__global__ __launch_bounds__(256) void b2_scatter(const int* __restrict__ ei,
                                                  const unsigned* __restrict__ blk_hist,
                                                  unsigned* __restrict__ bucketed,
                                                  int e_cnt, int chunk, int nbk) {
    __shared__ int cur[NBK_STRIDE];
    int b = blockIdx.x, t = threadIdx.x;
    for (int j = t; j < nbk; j += 256)
        cur[j] = (int)blk_hist[(size_t)b * NBK_STRIDE + j];
    __syncthreads();
    int lo = b * chunk, hi = min(lo + chunk, e_cnt);
    for (int e = lo + t; e < hi; e += 256) {
        int col = ei[e_cnt + e];
        int src = ei[e];
        int bkt = col >> BK_SHIFT;
        int pos = atomicAdd(&cur[bkt], 1);
        bucketed[pos] = ((unsigned)src << BK_SHIFT) | (unsigned)(col & (BK_COLS - 1));
    }
}

// ---------------------------------------------------------------------------
// Sort pass C: one block per bucket -> exact CSR.
// ---------------------------------------------------------------------------
__global__ __launch_bounds__(256) void c_csr(const unsigned* __restrict__ bucketed,
                                             const unsigned* __restrict__ bucket_offsets,
                                             int* __restrict__ offsets,
                                             unsigned* __restrict__ srcs,
                                             int n, int e_cnt) {
    __shared__ unsigned sE[CCAP];
    __shared__ int sh[BK_COLS];
    __shared__ int sc[BK_COLS];
    __shared__ int pos_[BK_COLS];
    int b = blockIdx.x, t = threadIdx.x;
    int base = (int)bucket_offsets[b];
    int cnt = (int)bucket_offsets[b + 1] - base;
    bool fits = (cnt <= CCAP);
    if (fits)
        for (int i = t; i < cnt; i += 256) sE[i] = bucketed[base + i];
    if (t < BK_COLS) sh[t] = 0;
    __syncthreads();
    for (int i = t; i < cnt; i += 256) {
        unsigned p = fits ? sE[i] : bucketed[base + i];
        atomicAdd(&sh[p & (BK_COLS - 1)], 1);
    }
    __syncthreads();
    if (t < BK_COLS) sc[t] = sh[t];
    __syncthreads();
    for (int d = 1; d < BK_COLS; d <<= 1) {
        int u = 0;
        if (t < BK_COLS && t >= d) u = sc[t - d];
        __syncthreads();
        if (t < BK_COLS) sc[t] += u;
        __syncthreads();
    }
    if (t < BK_COLS) {
        int pre = sc[t] - sh[t];
        int gc = b * BK_COLS + t;
        if (gc < n) offsets[gc] = base + pre;
        pos_[t] = pre;
    }
    if (b == 0 && t == 0) offsets[n] = e_cnt;
    __syncthreads();
    for (int i = t; i < cnt; i += 256) {
        unsigned p = fits ? sE[i] : bucketed[base + i];
        int lc = (int)(p & (BK_COLS - 1));
        int q = atomicAdd(&pos_[lc], 1);
        srcs[base + q] = p >> BK_SHIFT;
    }
}

// ---------------------------------------------------------------------------
// fused gather + self-loop + bias + log-softmax; one wave per node.
// xw read as bf16 (128 B per edge row).
// ---------------------------------------------------------------------------
__global__ __launch_bounds__(256) void gather_kernel(const int* __restrict__ offsets,
                                                     const unsigned* __restrict__ srcs,
                                                     const float* __restrict__ d_e2m,
                                                     const float* __restrict__ d_e3p,
                                                     const unsigned short* __restrict__ xwb,
                                                     const float* __restrict__ gso2,
                                                     const float* __restrict__ b,
                                                     float* __restrict__ out, int n) {
    int lane = threadIdx.x & 63;
    int node = blockIdx.x * 4 + (threadIdx.x >> 6);
    if (node >= n) return;
    int lo = offsets[node], hi = offsets[node + 1];
    float xself = bf16_to_f32(xwb[(size_t)node * DOUT + lane]);
    float v = gso2[node] * xself + 2.0f * b[lane];
    float dn = d_e3p[node];
    float acc = 0.f;
    int i = lo;
    for (; i + 4 <= hi; i += 4) {
        unsigned s0 = srcs[i], s1 = srcs[i + 1], s2 = srcs[i + 2], s3 = srcs[i + 3];
        float w0 = d_e2m[s0], w1 = d_e2m[s1], w2 = d_e2m[s2], w3 = d_e2m[s3];
        float a0 = bf16_to_f32(xwb[(size_t)s0 * DOUT + lane]);
        float a1 = bf16_to_f32(xwb[(size_t)s1 * DOUT + lane]);
        float a2 = bf16_to_f32(xwb[(size_t)s2 * DOUT + lane]);
        float a3 = bf16_to_f32(xwb[(size_t)s3 * DOUT + lane]);
        acc += w0 * a0 + w1 * a1 + w2 * a2 + w3 * a3;
    }
    for (; i < hi; ++i) {
        unsigned s = srcs[i];
        acc += d_e2m[s] * bf16_to_f32(xwb[(size_t)s * DOUT + lane]);
    }
    v += dn * acc;
    float m = v;
#pragma unroll
    for (int d = 1; d < 64; d <<= 1) m = fmaxf(m, __shfl_xor(m, d));
    float s = expf(v - m);
#pragma unroll
    for (int d = 1; d < 64; d <<= 1) s += __shfl_xor(s, d);
    out[(size_t)node * DOUT + lane] = v - m - logf(s);
}

// ---------------------------------------------------------------------------
extern "C" void kernel_launch(void* const* d_in, const int* in_sizes, int n_in,
                              void* d_out, int out_size, void* d_ws, size_t ws_size,
                              hipStream_t stream) {
    const float* x     = (const float*)d_in[0];
    const int*   ei    = (const int*)d_in[1];
    const float* diags = (const float*)d_in[3];
    const float* W     = (const float*)d_in[4];
    const float* b     = (const float*)d_in[5];
    const float* m1    = (const float*)d_in[6];
    const float* m2    = (const float*)d_in[7];
    const float* m3    = (const float*)d_in[8];
    const float* e1    = (const float*)d_in[9];
    const float* e2    = (const float*)d_in[10];
    const float* e3    = (const float*)d_in[11];
    float* out = (float*)d_out;

    const int n = in_sizes[3];            // 100000
    const int e_cnt = in_sizes[1] / 2;    // 1600000
    const int nbk = (n + BK_COLS - 1) >> BK_SHIFT;          // 782 buckets
    const int chunk = (e_cnt + NBLK - 1) / NBLK;            // 25000 edges/block

    char* ws = (char*)d_ws;
    // --- small-matrix region first (fixed offsets) ---
    float*    Wo   = (float*)ws;                 // 8192 floats = 32KB
    float*    gG   = (float*)(ws + 32768);       // 12 x 4096 floats
    float*    gT   = gG  + 4096;
    float*    gA   = gT  + 4096;
    float*    gAn  = gA  + 4096;
    float*    gA0  = gAn + 4096;
    float*    gP   = gA0 + 4096;
    float*    gPn  = gP  + 4096;
    float*    gB0  = gPn + 4096;
    float*    gB1  = gB0 + 4096;
    float*    gB2  = gB1 + 4096;
    float*    gB3  = gB2 + 4096;
    float*    gB4  = gB3 + 4096;
    float*    gSc  = gB4 + 4096;                 // 2 floats (pad to 64)
    // --- big arrays ---
    float*          d_e2m    = gSc + 64;               // n
    float*          d_e3p    = d_e2m + n;              // n
    float*          gso2     = d_e3p + n;              // n
    unsigned short* xwb      = (unsigned short*)(gso2 + n);   // n*64 bf16
    int*            offsets  = (int*)(xwb + (size_t)n * DOUT); // n+4
    unsigned*       srcs     = (unsigned*)(offsets + n + 4);   // e_cnt
    unsigned*       bucketed = srcs + e_cnt;                   // e_cnt
    unsigned*       blk_hist = bucketed + e_cnt;               // NBLK*1024
    unsigned*       boff     = blk_hist + (size_t)NBLK * NBK_STRIDE; // nbk+1

    // ---- Bjorck chain: small multi-block dispatches ------------------------
    gram_pass<<<8, 256, 0, stream>>>(W, gG);                              // G
    mm_pass<<<8, 256, 0, stream>>>(gG, nullptr, gG, gT, nullptr, nullptr); // H = G^2
    mm_pass<<<8, 256, 0, stream>>>(gT, nullptr, gT, gA, nullptr, nullptr); // H2 = G^4
    power_pass<<<1, 64, 0, stream>>>(gA, gSc);                            // sc, rs
    prep_pass<<<16, 256, 0, stream>>>(gG, gSc, gA0, gB0);                 // A0, B0
    mm_pass<<<8, 256, 0, stream>>>(gA0, nullptr, gB0, gT, nullptr, nullptr); // T = A0@B0
    mm_pass<<<8, 256, 0, stream>>>(gT, nullptr, gB0, gA, nullptr, gB1);   // A1 (+B1)
    mm_pass<<<16, 256, 0, stream>>>(gB0, gA, gB1, gP, gT, nullptr);       // P=B0B1, T=A1B1
    mm_pass<<<8, 256, 0, stream>>>(gT, nullptr, gB1, gAn, nullptr, gB2);  // A2 (+B2)
    mm_pass<<<16, 256, 0, stream>>>(gP, gAn, gB2, gPn, gT, nullptr);      // P=PB2, T=A2B2
    mm_pass<<<8, 256, 0, stream>>>(gT, nullptr, gB2, gA, nullptr, gB3);   // A3 (+B3)
    mm_pass<<<16, 256, 0, stream>>>(gPn, gA, gB3, gP, gT, nullptr);       // P=PB3, T=A3B3
    mm_pass<<<8, 256, 0, stream>>>(gT, nullptr, gB3, gAn, nullptr, gB4);  // A4 (+B4)
    mm_pass<<<8, 256, 0, stream>>>(gP, nullptr, gB4, gPn, nullptr, nullptr); // P final
    wo_pass<<<8, 256, 0, stream>>>(W, gPn, gSc, Wo);                      // Wo

    // ---- node prep + feature transform ------------------------------------
    node_prep<<<(n + 255) / 256, 256, 0, stream>>>(diags, m1, m2, m3, e1, e2, e3,
                                                   d_e2m, d_e3p, gso2, n);
    xw_kernel<<<(n + XN - 1) / XN, 256, 0, stream>>>(x, Wo, xwb, n);
    // ---- two-level bucket sort -> CSR --------------------------------------
    b1_hist<<<NBLK, 256, 0, stream>>>(ei, blk_hist, e_cnt, chunk, nbk);
    s_scan<<<1, 1024, 0, stream>>>(blk_hist, boff, nbk, e_cnt);
    b2_scatter<<<NBLK, 256, 0, stream>>>(ei, blk_hist, bucketed, e_cnt, chunk, nbk);
    c_csr<<<nbk, 256, 0, stream>>>(bucketed, boff, offsets, srcs, n, e_cnt);
    // ---- fused gather + softmax --------------------------------------------
    gather_kernel<<<(n + 3) / 4, 256, 0, stream>>>(offsets, srcs, d_e2m, d_e3p,
                                                   xwb, gso2, b, out, n);
}

// Round 12
// 262.171 us; speedup vs baseline: 1.5852x; 1.0111x over previous
//
#include <hip/hip_runtime.h>
#include <math.h>

#define DIN 128
#define DOUT 64

#define NBLK 64             // binning blocks
#define BK_SHIFT 7          // 128 cols per bucket
#define BK_COLS 128
#define NBK_STRIDE 1024     // blk_hist row stride (buckets padded)
#define CCAP 4096           // max edges per bucket staged in LDS (mean ~2046)

__device__ __forceinline__ float safe_pow(float d, float e) {
    float p = powf(d, e);
    return isinf(p) ? 0.0f : p;
}

__device__ __forceinline__ float dot4(float4 a, float4 b) {
    return a.x * b.x + a.y * b.y + a.z * b.z + a.w * b.w;
}

// fp32 -> bf16 (round-to-nearest-even), as raw ushort
__device__ __forceinline__ unsigned short f32_to_bf16(float f) {
    unsigned bits = __float_as_uint(f);
    unsigned r = (bits + 0x7FFFu + ((bits >> 16) & 1u)) >> 16;
    return (unsigned short)r;
}
// bf16 (raw ushort) -> fp32
__device__ __forceinline__ float bf16_to_f32(unsigned short u) {
    return __uint_as_float((unsigned)u << 16);
}

// ---------------------------------------------------------------------------
// Plain multi-block 64x64 matmul: C = A @ B, Bsrc SYMMETRIC (rows read as
// cols). grid 8 (single) or 16 (dual: blocks 8..15 compute C2 = A2 @ B).
// Optional CB output (single passes only): CB = 1.5I - 0.5*C.
// ---------------------------------------------------------------------------
__global__ __launch_bounds__(256) void mm_pass(const float* A1, const float* A2,
                                               const float* Bsrc,
                                               float* C1, float* C2, float* CB) {
    int t = threadIdx.x;
    bool second = (blockIdx.x >= 8);
    int blk = blockIdx.x & 7;
    const float* As = second ? A2 : A1;
    float* Cs = second ? C2 : C1;
    int c = t & 63;
    int r0 = blk * 8 + (t >> 6) * 2;
    float acc0 = 0.f, acc1 = 0.f;
#pragma unroll
    for (int k4 = 0; k4 < 16; ++k4) {
        float4 b  = *(const float4*)&Bsrc[c * 64 + k4 * 4];
        float4 a0 = *(const float4*)&As[r0 * 64 + k4 * 4];
        float4 a1 = *(const float4*)&As[(r0 + 1) * 64 + k4 * 4];
        acc0 += dot4(a0, b);
        acc1 += dot4(a1, b);
    }
    Cs[r0 * 64 + c] = acc0;
    Cs[(r0 + 1) * 64 + c] = acc1;
    if (CB != nullptr && !second) {
        CB[r0 * 64 + c]       = ((r0 == c)     ? 1.5f : 0.0f) - 0.5f * acc0;
        CB[(r0 + 1) * 64 + c] = ((r0 + 1 == c) ? 1.5f : 0.0f) - 0.5f * acc1;
    }
}

// ---------------------------------------------------------------------------
// G = W @ W^T (64x64, K=128), 8 blocks.
// ---------------------------------------------------------------------------
__global__ __launch_bounds__(256) void gram_pass(const float* W, float* G) {
    int t = threadIdx.x;
    int c = t & 63;
    int r0 = blockIdx.x * 8 + (t >> 6) * 2;
    float acc0 = 0.f, acc1 = 0.f;
#pragma unroll
    for (int k4 = 0; k4 < 32; ++k4) {
        float4 b  = *(const float4*)&W[c * 128 + k4 * 4];
        float4 a0 = *(const float4*)&W[r0 * 128 + k4 * 4];
        float4 a1 = *(const float4*)&W[(r0 + 1) * 128 + k4 * 4];
        acc0 += dot4(a0, b);
        acc1 += dot4(a1, b);
    }
    G[r0 * 64 + c] = acc0;
    G[(r0 + 1) * 64 + c] = acc1;
}

// ---------------------------------------------------------------------------
// power iteration on H2 = G^4 (trace-scaled, 8 raw iters + Rayleigh), 1 wave.
// ---------------------------------------------------------------------------
__global__ __launch_bounds__(64) void power_pass(const float* gH2, float* gSc) {
    int t = threadIdx.x;
    float tr = gH2[t * 65];
#pragma unroll
    for (int d = 1; d < 64; d <<= 1) tr += __shfl_xor(tr, d);
    float inv_tr = 1.0f / tr;
    float4 g4[16];
#pragma unroll
    for (int j4 = 0; j4 < 16; ++j4) {
        float4 v = *(const float4*)&gH2[t * 64 + j4 * 4];
        v.x *= inv_tr; v.y *= inv_tr; v.z *= inv_tr; v.w *= inv_tr;
        g4[j4] = v;
    }
    unsigned h = (unsigned)t * 2654435761u;
    float xv = 0.5f + (float)((h >> 17) & 0x7fff) * (1.0f / 32768.0f);
    float yv = 0.f;
    for (int it = 0; it < 8; ++it) {
        float p0 = 0.f, p1 = 0.f, p2 = 0.f, p3 = 0.f;
#pragma unroll
        for (int j4 = 0; j4 < 16; ++j4) {
            float4 xx;
            xx.x = __shfl(xv, j4 * 4 + 0);
            xx.y = __shfl(xv, j4 * 4 + 1);
            xx.z = __shfl(xv, j4 * 4 + 2);
            xx.w = __shfl(xv, j4 * 4 + 3);
            float dd = dot4(g4[j4], xx);
            if (j4 < 4) p0 += dd; else if (j4 < 8) p1 += dd;
            else if (j4 < 12) p2 += dd; else p3 += dd;
        }
        yv = (p0 + p1) + (p2 + p3);
        if (it < 7) xv = yv;
    }
    float num = xv * yv, den = xv * xv;
#pragma unroll
    for (int d = 1; d < 64; d <<= 1) {
        num += __shfl_xor(num, d);
        den += __shfl_xor(den, d);
    }
    if (t == 0) {
        float lam_h2 = tr * num / den;        // = sigma^8
        float sig = powf(lam_h2, 0.125f);
        gSc[0] = 1.0f / (1.1f * sig);
        gSc[1] = 1.0f / (1.21f * sig * sig);
    }
}

// ---------------------------------------------------------------------------
// prep: A0 = rs*G;  B0 = 1.5I - 0.5*A0
// ---------------------------------------------------------------------------
__global__ __launch_bounds__(256) void prep_pass(const float* gG, const float* gSc,
                                                 float* gA0, float* gB0) {
    int idx = blockIdx.x * 256 + threadIdx.x;
    if (idx >= 4096) return;
    float rs = gSc[1];
    int r = idx >> 6, c = idx & 63;
    float a0 = rs * gG[idx];
    gA0[idx] = a0;
    gB0[idx] = ((r == c) ? 1.5f : 0.0f) - 0.5f * a0;
}

// ---------------------------------------------------------------------------
// Wo = sc * P @ W  (64x128), 8 blocks.
// ---------------------------------------------------------------------------
__global__ __launch_bounds__(256) void wo_pass(const float* W, const float* P,
                                               const float* gSc, float* Wo) {
    int t = threadIdx.x;
    int c = t & 63;
    int r0 = blockIdx.x * 8 + (t >> 6) * 2;
    float a00 = 0.f, a01 = 0.f, a10 = 0.f, a11 = 0.f;
#pragma unroll 4
    for (int j = 0; j < 64; ++j) {
        float p0 = P[r0 * 64 + j];
        float p1 = P[(r0 + 1) * 64 + j];
        float w0 = W[j * 128 + c];
        float w1 = W[j * 128 + c + 64];
        a00 += p0 * w0; a01 += p0 * w1;
        a10 += p1 * w0; a11 += p1 * w1;
    }
    float sc = gSc[0];
    Wo[r0 * 128 + c]            = sc * a00;
    Wo[r0 * 128 + c + 64]       = sc * a01;
    Wo[(r0 + 1) * 128 + c]      = sc * a10;
    Wo[(r0 + 1) * 128 + c + 64] = sc * a11;
}

// ---------------------------------------------------------------------------
// per-node prep
// ---------------------------------------------------------------------------
__global__ void node_prep(const float* __restrict__ diags,
                          const float* m1, const float* m2, const float* m3,
                          const float* e1, const float* e2, const float* e3,
                          float* __restrict__ d_e2m, float* __restrict__ d_e3p,
                          float* __restrict__ gso2, int n) {
    int i = blockIdx.x * blockDim.x + threadIdx.x;
    if (i >= n) return;
    float d = diags[i];
    float p1 = safe_pow(d, e1[0]);
    float p2 = safe_pow(d, e2[0]);
    float p3 = safe_pow(d, e3[0]);
    float vm2 = m2[0];
    d_e2m[i] = vm2 * p2;
    d_e3p[i] = p3;
    gso2[i] = m1[0] * p1 + vm2 * p2 * p3 + m3[0];
}

// ---------------------------------------------------------------------------
// xw = x @ Wo^T — register-tiled GEMM; OUTPUT IN BF16.
// ---------------------------------------------------------------------------
#define XN 64
#define XS 132
__global__ __launch_bounds__(256) void xw_kernel(const float* __restrict__ x,
                                                 const float* __restrict__ Wo,
                                                 unsigned short* __restrict__ xwb,
                                                 int n) {
    __shared__ __align__(16) float xs[XN * XS];
    __shared__ __align__(16) float ws[DOUT * XS];
    int t = threadIdx.x;
    int base = blockIdx.x * XN;
    for (int f = t; f < DOUT * (DIN / 4); f += 256) {
        int r = f >> 5, c = f & 31;
        *(float4*)&ws[r * XS + c * 4] = *(const float4*)&Wo[r * DIN + c * 4];
    }
    for (int f = t; f < XN * (DIN / 4); f += 256) {
        int r = f >> 5, c = f & 31;
        int node = base + r;
        float4 v = make_float4(0.f, 0.f, 0.f, 0.f);
        if (node < n) v = *(const float4*)&x[(size_t)node * DIN + c * 4];
        *(float4*)&xs[r * XS + c * 4] = v;
    }
    __syncthreads();
    int tn = t >> 4;
    int td = t & 15;
    float acc[4][4] = {};
#pragma unroll 2
    for (int k4 = 0; k4 < DIN / 4; ++k4) {
        float4 a[4], w[4];
#pragma unroll
        for (int r = 0; r < 4; ++r) a[r] = *(const float4*)&xs[(tn * 4 + r) * XS + k4 * 4];
#pragma unroll
        for (int c = 0; c < 4; ++c) w[c] = *(const float4*)&ws[(td + c * 16) * XS + k4 * 4];
#pragma unroll
        for (int r = 0; r < 4; ++r)
#pragma unroll
            for (int c = 0; c < 4; ++c) acc[r][c] += dot4(a[r], w[c]);
    }
#pragma unroll
    for (int r = 0; r < 4; ++r) {
        int node = base + tn * 4 + r;
        if (node >= n) break;
#pragma unroll
        for (int c = 0; c < 4; ++c)
            xwb[(size_t)node * DOUT + td + c * 16] = f32_to_bf16(acc[r][c]);
    }
}

// ---------------------------------------------------------------------------
// Sort pass B1: per-block bucket histograms (bucket = col >> 7).
// ---------------------------------------------------------------------------
__global__ __launch_bounds__(256) void b1_hist(const int* __restrict__ ei,
                                               unsigned* __restrict__ blk_hist,
                                               int e_cnt, int chunk, int nbk) {
    __shared__ int h[NBK_STRIDE];
    int b = blockIdx.x, t = threadIdx.x;
    for (int j = t; j < NBK_STRIDE; j += 256) h[j] = 0;
    __syncthreads();
    int lo = b * chunk, hi = min(lo + chunk, e_cnt);
    for (int e = lo + t; e < hi; e += 256)
        atomicAdd(&h[ei[e_cnt + e] >> BK_SHIFT], 1);
    __syncthreads();
    for (int j = t; j < nbk; j += 256)
        blk_hist[(size_t)b * NBK_STRIDE + j] = (unsigned)h[j];
}

// ---------------------------------------------------------------------------
// Sort pass S: scan bucket totals -> bucket_offsets + per-(block,bucket) bases.
// ---------------------------------------------------------------------------
__global__ __launch_bounds__(1024) void s_scan(unsigned* __restrict__ blk_hist,
                                               unsigned* __restrict__ bucket_offsets,
                                               int nbk, int e_cnt) {
    __shared__ int tot[1024];
    int t = threadIdx.x;
    int total = 0;
    if (t < nbk) {
        int run = 0;
        for (int b = 0; b < NBLK; ++b) {
            size_t idx = (size_t)b * NBK_STRIDE + t;
            int v = (int)blk_hist[idx];
            blk_hist[idx] = (unsigned)run;
            run += v;
        }
        total = run;
    }
    tot[t] = total;
    __syncthreads();
    for (int d = 1; d < 1024; d <<= 1) {
        int u = (t >= d) ? tot[t - d] : 0;
        __syncthreads();
        tot[t] += u;
        __syncthreads();
    }
    int excl = tot[t] - total;
    if (t < nbk) {
        bucket_offsets[t] = (unsigned)excl;
        for (int b = 0; b < NBLK; ++b)
            blk_hist[(size_t)b * NBK_STRIDE + t] += (unsigned)excl;
    }
    if (t == 0) bucket_offsets[nbk] = (unsigned)e_cnt;
}

// ---------------------------------------------------------------------------
// Sort pass B2: scatter packed (src<<7 | lcol) into reserved per-block runs.
// ---------------------------------------------------------------------------
__global__ __launch_bounds__(256) void b2_scatter(const int* __restrict__ ei,
                                                  const unsigned* __restrict__ blk_hist,
                                                  unsigned* __restrict__ bucketed,
                                                  int e_cnt, int chunk, int nbk) {
    __shared__ int cur[NBK_STRIDE];
    int b = blockIdx.x, t = threadIdx.x;
    for (int j = t; j < nbk; j += 256)
        cur[j] = (int)blk_hist[(size_t)b * NBK_STRIDE + j];
    __syncthreads();
    int lo = b * chunk, hi = min(lo + chunk, e_cnt);
    for (int e = lo + t; e < hi; e += 256) {
        int col = ei[e_cnt + e];
        int src = ei[e];
        int bkt = col >> BK_SHIFT;
        int pos = atomicAdd(&cur[bkt], 1);
        bucketed[pos] = ((unsigned)src << BK_SHIFT) | (unsigned)(col & (BK_COLS - 1));
    }
}

// ---------------------------------------------------------------------------
// Sort pass C: one block per bucket -> exact CSR. Emits (src, weight_f32)
// uint2 pairs so the gather needs NO random d_e2m lookups (round-11 lesson:
// gather was latency-bound on its dependent scalar-load chain).
// ---------------------------------------------------------------------------
__global__ __launch_bounds__(256) void c_csr(const unsigned* __restrict__ bucketed,
                                             const unsigned* __restrict__ bucket_offsets,
                                             const float* __restrict__ d_e2m,
                                             int* __restrict__ offsets,
                                             uint2* __restrict__ pairs,
                                             int n, int e_cnt) {
    __shared__ unsigned sE[CCAP];
    __shared__ int sh[BK_COLS];
    __shared__ int sc[BK_COLS];
    __shared__ int pos_[BK_COLS];
    int b = blockIdx.x, t = threadIdx.x;
    int base = (int)bucket_offsets[b];
    int cnt = (int)bucket_offsets[b + 1] - base;
    bool fits = (cnt <= CCAP);
    if (fits)
        for (int i = t; i < cnt; i += 256) sE[i] = bucketed[base + i];
    if (t < BK_COLS) sh[t] = 0;
    __syncthreads();
    for (int i = t; i < cnt; i += 256) {
        unsigned p = fits ? sE[i] : bucketed[base + i];
        atomicAdd(&sh[p & (BK_COLS - 1)], 1);
    }
    __syncthreads();
    if (t < BK_COLS) sc[t] = sh[t];
    __syncthreads();
    for (int d = 1; d < BK_COLS; d <<= 1) {
        int u = 0;
        if (t < BK_COLS && t >= d) u = sc[t - d];
        __syncthreads();
        if (t < BK_COLS) sc[t] += u;
        __syncthreads();
    }
    if (t < BK_COLS) {
        int pre = sc[t] - sh[t];
        int gc = b * BK_COLS + t;
        if (gc < n) offsets[gc] = base + pre;
        pos_[t] = pre;
    }
    if (b == 0 && t == 0) offsets[n] = e_cnt;
    __syncthreads();
    for (int i = t; i < cnt; i += 256) {
        unsigned p = fits ? sE[i] : bucketed[base + i];
        int lc = (int)(p & (BK_COLS - 1));
        unsigned s = p >> BK_SHIFT;
        int q = atomicAdd(&pos_[lc], 1);
        uint2 o;
        o.x = s;
        o.y = __float_as_uint(d_e2m[s]);
        pairs[base + q] = o;
    }
}

// ---------------------------------------------------------------------------
// fused gather + self-loop + bias + log-softmax; one wave per node.
// Edge metadata = sequential (src, w_f32) uint2 (wave-uniform scalar loads);
// xw rows bf16. Unroll 8 with dual accumulators for MLP.
// ---------------------------------------------------------------------------
__global__ __launch_bounds__(256) void gather_kernel(const int* __restrict__ offsets,
                                                     const uint2* __restrict__ pairs,
                                                     const float* __restrict__ d_e3p,
                                                     const unsigned short* __restrict__ xwb,
                                                     const float* __restrict__ gso2,
                                                     const float* __restrict__ b,
                                                     float* __restrict__ out, int n) {
    unsigned lane = threadIdx.x & 63;
    int node = blockIdx.x * 4 + (threadIdx.x >> 6);
    if (node >= n) return;
    int lo = offsets[node], hi = offsets[node + 1];
    float xself = bf16_to_f32(xwb[(size_t)node * DOUT + lane]);
    float v = gso2[node] * xself + 2.0f * b[lane];
    float dn = d_e3p[node];
    float accA = 0.f, accB = 0.f;
    int i = lo;
    for (; i + 8 <= hi; i += 8) {
        uint2 p0 = pairs[i + 0], p1 = pairs[i + 1], p2 = pairs[i + 2], p3 = pairs[i + 3];
        uint2 p4 = pairs[i + 4], p5 = pairs[i + 5], p6 = pairs[i + 6], p7 = pairs[i + 7];
        float a0 = bf16_to_f32(xwb[p0.x * 64u + lane]);
        float a1 = bf16_to_f32(xwb[p1.x * 64u + lane]);
        float a2 = bf16_to_f32(xwb[p2.x * 64u + lane]);
        float a3 = bf16_to_f32(xwb[p3.x * 64u + lane]);
        float a4 = bf16_to_f32(xwb[p4.x * 64u + lane]);
        float a5 = bf16_to_f32(xwb[p5.x * 64u + lane]);
        float a6 = bf16_to_f32(xwb[p6.x * 64u + lane]);
        float a7 = bf16_to_f32(xwb[p7.x * 64u + lane]);
        accA += __uint_as_float(p0.y) * a0 + __uint_as_float(p1.y) * a1
              + __uint_as_float(p2.y) * a2 + __uint_as_float(p3.y) * a3;
        accB += __uint_as_float(p4.y) * a4 + __uint_as_float(p5.y) * a5
              + __uint_as_float(p6.y) * a6 + __uint_as_float(p7.y) * a7;
    }
    for (; i + 2 <= hi; i += 2) {
        uint2 p0 = pairs[i + 0], p1 = pairs[i + 1];
        float a0 = bf16_to_f32(xwb[p0.x * 64u + lane]);
        float a1 = bf16_to_f32(xwb[p1.x * 64u + lane]);
        accA += __uint_as_float(p0.y) * a0;
        accB += __uint_as_float(p1.y) * a1;
    }
    if (i < hi) {
        uint2 p = pairs[i];
        accA += __uint_as_float(p.y) * bf16_to_f32(xwb[p.x * 64u + lane]);
    }
    v += dn * (accA + accB);
    float m = v;
#pragma unroll
    for (int d = 1; d < 64; d <<= 1) m = fmaxf(m, __shfl_xor(m, d));
    float s = expf(v - m);
#pragma unroll
    for (int d = 1; d < 64; d <<= 1) s += __shfl_xor(s, d);
    out[(size_t)node * DOUT + lane] = v - m - logf(s);
}

// ---------------------------------------------------------------------------
extern "C" void kernel_launch(void* const* d_in, const int* in_sizes, int n_in,
                              void* d_out, int out_size, void* d_ws, size_t ws_size,
                              hipStream_t stream) {
    const float* x     = (const float*)d_in[0];
    const int*   ei    = (const int*)d_in[1];
    const float* diags = (const float*)d_in[3];
    const float* W     = (const float*)d_in[4];
    const float* b     = (const float*)d_in[5];
    const float* m1    = (const float*)d_in[6];
    const float* m2    = (const float*)d_in[7];
    const float* m3    = (const float*)d_in[8];
    const float* e1    = (const float*)d_in[9];
    const float* e2    = (const float*)d_in[10];
    const float* e3    = (const float*)d_in[11];
    float* out = (float*)d_out;

    const int n = in_sizes[3];            // 100000
    const int e_cnt = in_sizes[1] / 2;    // 1600000
    const int nbk = (n + BK_COLS - 1) >> BK_SHIFT;          // 782 buckets
    const int chunk = (e_cnt + NBLK - 1) / NBLK;            // 25000 edges/block

    char* ws = (char*)d_ws;
    // --- small-matrix region first (fixed offsets) ---
    float*    Wo   = (float*)ws;                 // 8192 floats = 32KB
    float*    gG   = (float*)(ws + 32768);       // 12 x 4096 floats
    float*    gT   = gG  + 4096;
    float*    gA   = gT  + 4096;
    float*    gAn  = gA  + 4096;
    float*    gA0  = gAn + 4096;
    float*    gP   = gA0 + 4096;
    float*    gPn  = gP  + 4096;
    float*    gB0  = gPn + 4096;
    float*    gB1  = gB0 + 4096;
    float*    gB2  = gB1 + 4096;
    float*    gB3  = gB2 + 4096;
    float*    gB4  = gB3 + 4096;
    float*    gSc  = gB4 + 4096;                 // 2 floats (pad to 64)
    // --- big arrays ---
    float*          d_e2m    = gSc + 64;               // n
    float*          d_e3p    = d_e2m + n;              // n
    float*          gso2     = d_e3p + n;              // n
    unsigned short* xwb      = (unsigned short*)(gso2 + n);   // n*64 bf16
    int*            offsets  = (int*)(xwb + (size_t)n * DOUT); // n+4
    unsigned*       bucketed = (unsigned*)(offsets + n + 4);   // e_cnt
    unsigned*       blk_hist = bucketed + e_cnt;               // NBLK*1024
    unsigned*       boff     = blk_hist + (size_t)NBLK * NBK_STRIDE; // nbk+1
    uintptr_t pp = ((uintptr_t)(boff + nbk + 8) + 15) & ~(uintptr_t)15;
    uint2*          pairs    = (uint2*)pp;                     // e_cnt (8B)

    // ---- Bjorck chain: small multi-block dispatches ------------------------
    gram_pass<<<8, 256, 0, stream>>>(W, gG);                              // G
    mm_pass<<<8, 256, 0, stream>>>(gG, nullptr, gG, gT, nullptr, nullptr); // H = G^2
    mm_pass<<<8, 256, 0, stream>>>(gT, nullptr, gT, gA, nullptr, nullptr); // H2 = G^4
    power_pass<<<1, 64, 0, stream>>>(gA, gSc);                            // sc, rs
    prep_pass<<<16, 256, 0, stream>>>(gG, gSc, gA0, gB0);                 // A0, B0
    mm_pass<<<8, 256, 0, stream>>>(gA0, nullptr, gB0, gT, nullptr, nullptr); // T = A0@B0
    mm_pass<<<8, 256, 0, stream>>>(gT, nullptr, gB0, gA, nullptr, gB1);   // A1 (+B1)
    mm_pass<<<16, 256, 0, stream>>>(gB0, gA, gB1, gP, gT, nullptr);       // P=B0B1, T=A1B1
    mm_pass<<<8, 256, 0, stream>>>(gT, nullptr, gB1, gAn, nullptr, gB2);  // A2 (+B2)
    mm_pass<<<16, 256, 0, stream>>>(gP, gAn, gB2, gPn, gT, nullptr);      // P=PB2, T=A2B2
    mm_pass<<<8, 256, 0, stream>>>(gT, nullptr, gB2, gA, nullptr, gB3);   // A3 (+B3)
    mm_pass<<<16, 256, 0, stream>>>(gPn, gA, gB3, gP, gT, nullptr);       // P=PB3, T=A3B3
    mm_pass<<<8, 256, 0, stream>>>(gT, nullptr, gB3, gAn, nullptr, gB4);  // A4 (+B4)
    mm_pass<<<8, 256, 0, stream>>>(gP, nullptr, gB4, gPn, nullptr, nullptr); // P final
    wo_pass<<<8, 256, 0, stream>>>(W, gPn, gSc, Wo);                      // Wo

    // ---- node prep + feature transform ------------------------------------
    node_prep<<<(n + 255) / 256, 256, 0, stream>>>(diags, m1, m2, m3, e1, e2, e3,
                                                   d_e2m, d_e3p, gso2, n);
    xw_kernel<<<(n + XN - 1) / XN, 256, 0, stream>>>(x, Wo, xwb, n);
    // ---- two-level bucket sort -> CSR --------------------------------------
    b1_hist<<<NBLK, 256, 0, stream>>>(ei, blk_hist, e_cnt, chunk, nbk);
    s_scan<<<1, 1024, 0, stream>>>(blk_hist, boff, nbk, e_cnt);
    b2_scatter<<<NBLK, 256, 0, stream>>>(ei, blk_hist, bucketed, e_cnt, chunk, nbk);
    c_csr<<<nbk, 256, 0, stream>>>(bucketed, boff, d_e2m, offsets, pairs, n, e_cnt);
    // ---- fused gather + softmax --------------------------------------------
    gather_kernel<<<(n + 3) / 4, 256, 0, stream>>>(offsets, pairs, d_e3p,
                                                   xwb, gso2, b, out, n);
}